// Round 1
// baseline (3481.096 us; speedup 1.0000x reference)
//
#include <hip/hip_runtime.h>
#include <hip/hip_bf16.h>
#include <cstddef>

// Problem constants
#define Bc 2
#define Sc 2048
#define Ec 1024
#define Hc 16
#define HDc 64
#define DFFc 4096
#define ROWS (Bc * Sc)  // 4096

// ---------------------------------------------------------------------------
// Block-wide sum over 256 threads (4 waves of 64)
// ---------------------------------------------------------------------------
__device__ inline float block_sum256(float v, float* sb) {
    #pragma unroll
    for (int o = 32; o > 0; o >>= 1) v += __shfl_down(v, o, 64);
    int lane = threadIdx.x & 63, w = threadIdx.x >> 6;
    if (lane == 0) sb[w] = v;
    __syncthreads();
    float r = sb[0] + sb[1] + sb[2] + sb[3];
    __syncthreads();
    return r;
}

// ---------------------------------------------------------------------------
// LayerNorm: one block per row of E=1024. 256 threads, float4 per thread.
// ---------------------------------------------------------------------------
__global__ __launch_bounds__(256) void ln_kernel(const float* __restrict__ x,
                                                 const float* __restrict__ g,
                                                 const float* __restrict__ b,
                                                 float* __restrict__ out) {
    __shared__ float sb[4];
    int row = blockIdx.x;
    int t = threadIdx.x;
    const float* xr = x + (size_t)row * Ec;
    float4 v = ((const float4*)xr)[t];
    float s = v.x + v.y + v.z + v.w;
    float mu = block_sum256(s, sb) * (1.0f / Ec);
    float dx = v.x - mu, dy = v.y - mu, dz = v.z - mu, dw = v.w - mu;
    float ss = dx * dx + dy * dy + dz * dz + dw * dw;
    float var = block_sum256(ss, sb) * (1.0f / Ec);
    float inv = rsqrtf(var + 1e-5f);
    float4 gv = ((const float4*)g)[t];
    float4 bv = ((const float4*)b)[t];
    float4 o;
    o.x = dx * inv * gv.x + bv.x;
    o.y = dy * inv * gv.y + bv.y;
    o.z = dz * inv * gv.z + bv.z;
    o.w = dw * inv * gv.w + bv.w;
    ((float4*)(out + (size_t)row * Ec))[t] = o;
}

// ---------------------------------------------------------------------------
// gelu_new (tanh approximation), matches jax.nn.gelu(approximate=True)
// ---------------------------------------------------------------------------
__device__ inline float gelu_new(float x) {
    float x3 = x * x * x;
    return 0.5f * x * (1.0f + tanhf(0.7978845608028654f * (x + 0.044715f * x3)));
}

// ---------------------------------------------------------------------------
// C[M,N] = A[M,K] @ W[N,K]^T + bias, with epilogue:
//   EPI=0: none; EPI=1: + resid; EPI=2: gelu_new
// Tiles: 64x64x16, 256 threads, 4x4 microtile per thread. fp32.
// ---------------------------------------------------------------------------
template <int EPI>
__global__ __launch_bounds__(256) void gemm_nt(const float* __restrict__ A,
                                               const float* __restrict__ W,
                                               const float* __restrict__ bias,
                                               const float* __restrict__ R,
                                               float* __restrict__ C,
                                               int M, int N, int K) {
    constexpr int BM = 64, BN = 64, BK = 16;
    __shared__ float As[BK][BM + 4];
    __shared__ float Ws[BK][BN + 4];
    int t = threadIdx.x;
    int row0 = blockIdx.y * BM, col0 = blockIdx.x * BN;
    int tx = t & 15, ty = t >> 4;
    int lm = t >> 2;           // 0..63 tile row
    int lk = (t & 3) << 2;     // 0,4,8,12
    const float* Ap = A + (size_t)(row0 + lm) * K + lk;
    const float* Wp = W + (size_t)(col0 + lm) * K + lk;

    float acc[4][4] = {};

    for (int k0 = 0; k0 < K; k0 += BK) {
        float4 av = *(const float4*)(Ap + k0);
        float4 wv = *(const float4*)(Wp + k0);
        __syncthreads();
        As[lk + 0][lm] = av.x; As[lk + 1][lm] = av.y;
        As[lk + 2][lm] = av.z; As[lk + 3][lm] = av.w;
        Ws[lk + 0][lm] = wv.x; Ws[lk + 1][lm] = wv.y;
        Ws[lk + 2][lm] = wv.z; Ws[lk + 3][lm] = wv.w;
        __syncthreads();
        #pragma unroll
        for (int kk = 0; kk < BK; ++kk) {
            float4 a4 = *(const float4*)&As[kk][ty << 2];
            float4 b4 = *(const float4*)&Ws[kk][tx << 2];
            float ar[4] = {a4.x, a4.y, a4.z, a4.w};
            float br[4] = {b4.x, b4.y, b4.z, b4.w};
            #pragma unroll
            for (int i = 0; i < 4; ++i)
                #pragma unroll
                for (int j = 0; j < 4; ++j)
                    acc[i][j] = fmaf(ar[i], br[j], acc[i][j]);
        }
    }

    #pragma unroll
    for (int i = 0; i < 4; ++i) {
        int r = row0 + (ty << 2) + i;
        int c = col0 + (tx << 2);
        size_t off = (size_t)r * N + c;
        float4 o4;
        float* ov = &o4.x;
        #pragma unroll
        for (int j = 0; j < 4; ++j) {
            float v = acc[i][j] + bias[c + j];
            if (EPI == 1) v += R[off + j];
            if (EPI == 2) v = gelu_new(v);
            ov[j] = v;
        }
        *(float4*)(C + off) = o4;
    }
}

// ---------------------------------------------------------------------------
// Causal flash attention, fp32. qkv layout: [B,S, H*192] where per head:
// [0,64)=q, [64,128)=k, [128,192)=v. Output: [B,S,E] with feature = h*64+d.
// Block: 256 threads handles TQ=16 query rows for one (b,h).
// ---------------------------------------------------------------------------
__global__ __launch_bounds__(256) void attn_kernel(const float* __restrict__ qkv,
                                                   float* __restrict__ out) {
    constexpr int TQ = 16, TK = 64;
    int bh = blockIdx.y;
    int b = bh >> 4, h = bh & 15;
    int q0 = blockIdx.x * TQ;
    int t = threadIdx.x;
    int tx = t & 63, ty = t >> 6;

    __shared__ float Qs[TQ][HDc];        // 4 KB
    __shared__ float Ks[TK][HDc + 4];    // 17 KB (pad 4 for b128 reads)
    __shared__ float Vs[TK][HDc];        // 16 KB
    __shared__ float Scs[TQ][TK + 4];    // 4.25 KB
    __shared__ float mrow[TQ], lrow[TQ], arow[TQ];

    const float* base = qkv + (size_t)b * Sc * (3 * Ec) + h * (3 * HDc);

    for (int idx = t; idx < TQ * HDc; idx += 256) {
        int r = idx >> 6, d = idx & 63;
        Qs[r][d] = base[(size_t)(q0 + r) * (3 * Ec) + d];
    }
    if (t < TQ) { mrow[t] = -1e30f; lrow[t] = 0.0f; }

    float o[4] = {0.f, 0.f, 0.f, 0.f};

    int ntiles = (q0 + TQ - 1) / TK + 1;
    for (int kt = 0; kt < ntiles; ++kt) {
        int k0 = kt * TK;
        __syncthreads();
        for (int idx = t; idx < TK * HDc; idx += 256) {
            int r = idx >> 6, d = idx & 63;
            const float* kvrow = base + (size_t)(k0 + r) * (3 * Ec);
            Ks[r][d] = kvrow[64 + d];
            Vs[r][d] = kvrow[128 + d];
        }
        __syncthreads();

        // scores: thread (ty,tx) computes rows ty+4i, col tx
        #pragma unroll
        for (int i = 0; i < 4; ++i) {
            int r = ty + 4 * i;
            float acc = 0.f;
            #pragma unroll
            for (int d = 0; d < HDc; d += 4) {
                float4 qv = *(const float4*)&Qs[r][d];
                float4 kv = *(const float4*)&Ks[tx][d];
                acc += qv.x * kv.x + qv.y * kv.y + qv.z * kv.z + qv.w * kv.w;
            }
            acc *= 0.125f;  // 1/sqrt(64)
            if (k0 + tx > q0 + r) acc = -1e30f;
            Scs[r][tx] = acc;
        }
        __syncthreads();

        // online softmax per row (16 leader threads)
        if (t < TQ) {
            float m_old = mrow[t], mx = m_old;
            for (int j = 0; j < TK; ++j) mx = fmaxf(mx, Scs[t][j]);
            float al = __expf(m_old - mx);
            float sum = 0.f;
            for (int j = 0; j < TK; ++j) {
                float p = __expf(Scs[t][j] - mx);
                Scs[t][j] = p;
                sum += p;
            }
            mrow[t] = mx;
            lrow[t] = lrow[t] * al + sum;
            arow[t] = al;
        }
        __syncthreads();

        // O update: O[r][tx] = O*alpha + P[r][:] @ Vs[:][tx]
        #pragma unroll
        for (int i = 0; i < 4; ++i) {
            int r = ty + 4 * i;
            float acc = o[i] * arow[r];
            #pragma unroll
            for (int j = 0; j < TK; j += 4) {
                float4 p = *(const float4*)&Scs[r][j];
                acc += p.x * Vs[j + 0][tx] + p.y * Vs[j + 1][tx] +
                       p.z * Vs[j + 2][tx] + p.w * Vs[j + 3][tx];
            }
            o[i] = acc;
        }
    }

    #pragma unroll
    for (int i = 0; i < 4; ++i) {
        int r = ty + 4 * i;
        out[((size_t)(b * Sc + q0 + r)) * Ec + h * HDc + tx] = o[i] / lrow[r];
    }
}

// ---------------------------------------------------------------------------
extern "C" void kernel_launch(void* const* d_in, const int* in_sizes, int n_in,
                              void* d_out, int out_size, void* d_ws, size_t ws_size,
                              hipStream_t stream) {
    const float* x     = (const float*)d_in[0];
    const float* ln1_g = (const float*)d_in[1];
    const float* ln1_b = (const float*)d_in[2];
    const float* ln2_g = (const float*)d_in[3];
    const float* ln2_b = (const float*)d_in[4];
    const float* w_qkv = (const float*)d_in[5];
    const float* b_qkv = (const float*)d_in[6];
    const float* w_ao  = (const float*)d_in[7];
    const float* b_ao  = (const float*)d_in[8];
    const float* w_fc  = (const float*)d_in[9];
    const float* b_fc  = (const float*)d_in[10];
    const float* w_po  = (const float*)d_in[11];
    const float* b_po  = (const float*)d_in[12];
    float* out = (float*)d_out;

    // workspace layout (floats):
    //  h   : 4096*1024  (LN output, reused for both LNs)
    //  qkv : 4096*3072
    //  attn: 4096*1024
    //  x1  : 4096*1024  (x + attn_proj)
    //  ff aliases [qkv, attn): 4096*4096 floats exactly
    float* ws   = (float*)d_ws;
    float* h    = ws;
    float* qkv  = h + (size_t)ROWS * Ec;
    float* attn = qkv + (size_t)ROWS * (3 * Ec);
    float* x1   = attn + (size_t)ROWS * Ec;
    float* ff   = qkv;  // 4096*4096 = qkv(4096*3072) + attn(4096*1024)

    dim3 blk(256);

    // 1. h = LN1(x)
    ln_kernel<<<dim3(ROWS), blk, 0, stream>>>(x, ln1_g, ln1_b, h);
    // 2. qkv = h @ w_qkv^T + b_qkv
    gemm_nt<0><<<dim3((3 * Ec) / 64, ROWS / 64), blk, 0, stream>>>(
        h, w_qkv, b_qkv, nullptr, qkv, ROWS, 3 * Ec, Ec);
    // 3. attn = causal_attention(qkv)
    attn_kernel<<<dim3(Sc / 16, Bc * Hc), blk, 0, stream>>>(qkv, attn);
    // 4. x1 = x + attn @ w_ao^T + b_ao
    gemm_nt<1><<<dim3(Ec / 64, ROWS / 64), blk, 0, stream>>>(
        attn, w_ao, b_ao, x, x1, ROWS, Ec, Ec);
    // 5. h = LN2(x1)
    ln_kernel<<<dim3(ROWS), blk, 0, stream>>>(x1, ln2_g, ln2_b, h);
    // 6. ff = gelu(h @ w_fc^T + b_fc)
    gemm_nt<2><<<dim3(DFFc / 64, ROWS / 64), blk, 0, stream>>>(
        h, w_fc, b_fc, nullptr, ff, ROWS, DFFc, Ec);
    // 7. out = x1 + ff @ w_po^T + b_po
    gemm_nt<1><<<dim3(Ec / 64, ROWS / 64), blk, 0, stream>>>(
        ff, w_po, b_po, x1, out, ROWS, Ec, DFFc);
}

// Round 3
// 486.107 us; speedup vs baseline: 7.1612x; 7.1612x over previous
//
#include <hip/hip_runtime.h>
#include <cstddef>
#include <cstdint>

#define Bc 2
#define Sc 2048
#define Ec 1024
#define Hc 16
#define HDc 64
#define DFFc 4096
#define ROWS (Bc * Sc)  // 4096

typedef _Float16 half8v __attribute__((ext_vector_type(8)));  // 8 fp16 (4 VGPR)
typedef _Float16 half4v __attribute__((ext_vector_type(4)));
typedef float f32x4 __attribute__((ext_vector_type(4)));      // MFMA C/D frag
typedef _Float16 h16;

// async global->LDS, 16B per lane. LDS dest must be wave-uniform base + lane*16.
__device__ inline void gld_lds16(const void* g, void* l) {
    __builtin_amdgcn_global_load_lds(
        (const __attribute__((address_space(1))) void*)g,
        (__attribute__((address_space(3))) void*)l, 16, 0, 0);
}

__device__ inline float gelu_new(float x) {
    float x3 = x * x * x;
    return 0.5f * x * (1.0f + tanhf(0.7978845608028654f * (x + 0.044715f * x3)));
}

// ---------------------------------------------------------------------------
// fp32 -> fp16 convert (weights), n % 1024 == 0
// ---------------------------------------------------------------------------
__global__ __launch_bounds__(256) void cvt_kernel(const float* __restrict__ in,
                                                  h16* __restrict__ out, int n) {
    int i = (blockIdx.x * 256 + threadIdx.x) * 4;
    float4 v = *(const float4*)(in + i);
    half4v o;
    o.x = (h16)v.x; o.y = (h16)v.y; o.z = (h16)v.z; o.w = (h16)v.w;
    *(half4v*)(out + i) = o;
}

// ---------------------------------------------------------------------------
// LayerNorm: fp32 in, fp16 out. One block per row of E=1024.
// ---------------------------------------------------------------------------
__device__ inline float block_sum256(float v, float* sb) {
    #pragma unroll
    for (int o = 32; o > 0; o >>= 1) v += __shfl_down(v, o, 64);
    int lane = threadIdx.x & 63, w = threadIdx.x >> 6;
    if (lane == 0) sb[w] = v;
    __syncthreads();
    float r = sb[0] + sb[1] + sb[2] + sb[3];
    __syncthreads();
    return r;
}

__global__ __launch_bounds__(256) void ln_kernel(const float* __restrict__ x,
                                                 const float* __restrict__ g,
                                                 const float* __restrict__ b,
                                                 h16* __restrict__ out) {
    __shared__ float sb[4];
    int row = blockIdx.x;
    int t = threadIdx.x;
    const float* xr = x + (size_t)row * Ec;
    float4 v = ((const float4*)xr)[t];
    float s = v.x + v.y + v.z + v.w;
    float mu = block_sum256(s, sb) * (1.0f / Ec);
    float dx = v.x - mu, dy = v.y - mu, dz = v.z - mu, dw = v.w - mu;
    float ss = dx * dx + dy * dy + dz * dz + dw * dw;
    float var = block_sum256(ss, sb) * (1.0f / Ec);
    float inv = rsqrtf(var + 1e-5f);
    float4 gv = ((const float4*)g)[t];
    float4 bv = ((const float4*)b)[t];
    half4v o;
    o.x = (h16)(dx * inv * gv.x + bv.x);
    o.y = (h16)(dy * inv * gv.y + bv.y);
    o.z = (h16)(dz * inv * gv.z + bv.z);
    o.w = (h16)(dw * inv * gv.w + bv.w);
    ((half4v*)(out + (size_t)row * Ec))[t] = o;
}

// ---------------------------------------------------------------------------
// fp16 MFMA GEMM: C[M,N] = A[M,K] @ W[N,K]^T + bias (+epilogue)
// BN=128, BK=32, BM in {64,128}. 256 threads = 4 waves in 2x2.
// EPI: 0 none, 1 +R (fp32 resid), 2 gelu_new. OutT h16 or float.
// ---------------------------------------------------------------------------
template <int BM, int EPI, typename OutT>
__global__ __launch_bounds__(256) void gemm_mfma(
    const h16* __restrict__ A, const h16* __restrict__ W,
    const float* __restrict__ bias, const float* __restrict__ R,
    OutT* __restrict__ C, int M, int N, int K)
{
    constexpr int WM = BM / 2;   // wave row extent
    constexpr int MI = WM / 16;  // m-tiles per wave
    __shared__ h16 As[BM * 32];
    __shared__ h16 Ws[128 * 32];

    const int t = threadIdx.x;
    const int lane = t & 63, wv = t >> 6;
    const int wm = wv >> 1, wn = wv & 1;
    const int c15 = lane & 15, q = lane >> 4;
    const int row0 = blockIdx.y * BM, col0 = blockIdx.x * 128;
    const int arow = t >> 2, acol = (t & 3) << 3;  // staging row / col8

    f32x4 acc[MI][4];
    #pragma unroll
    for (int i = 0; i < MI; ++i)
        #pragma unroll
        for (int j = 0; j < 4; ++j)
            acc[i][j] = (f32x4){0.f, 0.f, 0.f, 0.f};

    for (int k0 = 0; k0 < K; k0 += 32) {
        __syncthreads();
        #pragma unroll
        for (int p = 0; p < BM / 64; ++p) {
            int r = p * 64 + arow;
            gld_lds16(A + (size_t)(row0 + r) * K + k0 + acol, &As[r * 32 + acol]);
        }
        #pragma unroll
        for (int p = 0; p < 2; ++p) {
            int r = p * 64 + arow;
            gld_lds16(W + (size_t)(col0 + r) * K + k0 + acol, &Ws[r * 32 + acol]);
        }
        __syncthreads();

        half8v af[MI], bf[4];
        #pragma unroll
        for (int i = 0; i < MI; ++i)
            af[i] = *(const half8v*)&As[(wm * WM + i * 16 + c15) * 32 + q * 8];
        #pragma unroll
        for (int j = 0; j < 4; ++j)
            bf[j] = *(const half8v*)&Ws[(wn * 64 + j * 16 + c15) * 32 + q * 8];
        #pragma unroll
        for (int i = 0; i < MI; ++i)
            #pragma unroll
            for (int j = 0; j < 4; ++j)
                acc[i][j] = __builtin_amdgcn_mfma_f32_16x16x32_f16(af[i], bf[j], acc[i][j], 0, 0, 0);
    }

    #pragma unroll
    for (int i = 0; i < MI; ++i) {
        #pragma unroll
        for (int j = 0; j < 4; ++j) {
            int col = col0 + wn * 64 + j * 16 + c15;
            float bv = bias[col];
            #pragma unroll
            for (int r = 0; r < 4; ++r) {
                int row = row0 + wm * WM + i * 16 + q * 4 + r;
                size_t off = (size_t)row * N + col;
                float v = acc[i][j][r] + bv;
                if (EPI == 1) v += R[off];
                if (EPI == 2) v = gelu_new(v);
                if (sizeof(OutT) == 2) ((h16*)C)[off] = (h16)v;
                else ((float*)C)[off] = v;
            }
        }
    }
}

// ---------------------------------------------------------------------------
// Causal flash attention, fp16 MFMA. qkv fp16 [B,S,H*192] (q|k|v per head).
// Block = 4 waves x 32 Q-rows = 128 Q rows per (b,h). K-tiles of 64.
// ---------------------------------------------------------------------------
__global__ __launch_bounds__(256) void attn_mfma(const h16* __restrict__ qkv,
                                                 h16* __restrict__ attn) {
    __shared__ h16 Ks[2 * 64 * 32];        // [kk][key][32d]      8 KB
    __shared__ h16 Vt[2 * 64 * 32];        // [kk][d][32key]      8 KB
    __shared__ h16 Ps[4 * 2 * 32 * 32];    // per-wave [kk][m][32key] 16 KB

    const int t = threadIdx.x;
    const int lane = t & 63, wv = t >> 6;
    const int c15 = lane & 15, q = lane >> 4;
    const int bh = blockIdx.y, b = bh >> 4, h = bh & 15;
    const int q0 = blockIdx.x * 128;
    const int wrow0 = q0 + wv * 32;

    const size_t hbase = (size_t)b * Sc * (3 * Ec) + (size_t)h * (3 * HDc);

    // Q fragments (register-resident whole kernel)
    half8v qf[2][2];
    #pragma unroll
    for (int i = 0; i < 2; ++i)
        #pragma unroll
        for (int kk = 0; kk < 2; ++kk) {
            int row = wrow0 + i * 16 + c15;
            qf[i][kk] = *(const half8v*)(qkv + hbase + (size_t)row * (3 * Ec) + kk * 32 + q * 8);
        }

    f32x4 O[2][4];
    #pragma unroll
    for (int i = 0; i < 2; ++i)
        #pragma unroll
        for (int n = 0; n < 4; ++n)
            O[i][n] = (f32x4){0.f, 0.f, 0.f, 0.f};
    float mi[2][4], li[2][4];
    #pragma unroll
    for (int i = 0; i < 2; ++i)
        #pragma unroll
        for (int r = 0; r < 4; ++r) { mi[i][r] = -3e38f; li[i][r] = 0.f; }

    const int wmax = wrow0 + 31;
    const int ntiles = q0 / 64 + 2;
    const int krow = t >> 2, kjj = t & 3;          // K staging
    const int vkey = t & 31, vd0 = (t >> 5) << 3;  // V staging

    for (int kt = 0; kt < ntiles; ++kt) {
        const int k0 = kt * 64;
        __syncthreads();
        // stage K halves via global_load_lds (dest chunk = p*256 + t -> lane-linear)
        #pragma unroll
        for (int p = 0; p < 2; ++p)
            gld_lds16(qkv + hbase + (size_t)(k0 + krow) * (3 * Ec) + HDc + p * 32 + kjj * 8,
                      &Ks[p * 2048 + krow * 32 + kjj * 8]);
        // stage V transposed (scalar b16 scatter)
        #pragma unroll
        for (int p = 0; p < 2; ++p) {
            half8v v8 = *(const half8v*)(qkv + hbase +
                          (size_t)(k0 + p * 32 + vkey) * (3 * Ec) + 2 * HDc + vd0);
            #pragma unroll
            for (int u = 0; u < 8; ++u)
                Vt[p * 2048 + (vd0 + u) * 32 + vkey] = v8[u];
        }
        __syncthreads();
        if (k0 > wmax) continue;  // fully-masked for this wave; barriers already done

        // S = Q K^T  (C layout: row = q*4+r, col = c15 within 16x16 tile)
        half8v kf[4][2];
        #pragma unroll
        for (int j = 0; j < 4; ++j)
            #pragma unroll
            for (int kk = 0; kk < 2; ++kk)
                kf[j][kk] = *(const half8v*)&Ks[kk * 2048 + (j * 16 + c15) * 32 + q * 8];
        f32x4 s[2][4];
        #pragma unroll
        for (int i = 0; i < 2; ++i)
            #pragma unroll
            for (int j = 0; j < 4; ++j) {
                f32x4 z = (f32x4){0.f, 0.f, 0.f, 0.f};
                z = __builtin_amdgcn_mfma_f32_16x16x32_f16(qf[i][0], kf[j][0], z, 0, 0, 0);
                s[i][j] = __builtin_amdgcn_mfma_f32_16x16x32_f16(qf[i][1], kf[j][1], z, 0, 0, 0);
            }

        // online softmax (rows live in 16-lane groups; xor-shuffle 1,2,4,8)
        #pragma unroll
        for (int i = 0; i < 2; ++i) {
            #pragma unroll
            for (int r = 0; r < 4; ++r) {
                int row = wrow0 + i * 16 + q * 4 + r;
                float sv[4]; float mx = mi[i][r];
                #pragma unroll
                for (int j = 0; j < 4; ++j) {
                    float v = s[i][j][r] * 0.125f;
                    int col = k0 + j * 16 + c15;
                    v = (col <= row) ? v : -3e38f;
                    sv[j] = v;
                    mx = fmaxf(mx, v);
                }
                #pragma unroll
                for (int m = 1; m < 16; m <<= 1) mx = fmaxf(mx, __shfl_xor(mx, m, 64));
                float al = __expf(mi[i][r] - mx);
                float ps = 0.f;
                #pragma unroll
                for (int j = 0; j < 4; ++j) {
                    float p = __expf(sv[j] - mx);
                    ps += p;
                    Ps[wv * 2048 + (j >> 1) * 1024 + (i * 16 + q * 4 + r) * 32 + (j & 1) * 16 + c15] = (h16)p;
                }
                #pragma unroll
                for (int m = 1; m < 16; m <<= 1) ps += __shfl_xor(ps, m, 64);
                mi[i][r] = mx;
                li[i][r] = li[i][r] * al + ps;
                #pragma unroll
                for (int n = 0; n < 4; ++n) O[i][n][r] *= al;
            }
        }

        // O += P V   (P via per-wave LDS round-trip into A-layout)
        half8v pa[2][2];
        #pragma unroll
        for (int i = 0; i < 2; ++i)
            #pragma unroll
            for (int kk = 0; kk < 2; ++kk)
                pa[i][kk] = *(const half8v*)&Ps[wv * 2048 + kk * 1024 + (i * 16 + c15) * 32 + q * 8];
        #pragma unroll
        for (int n = 0; n < 4; ++n) {
            half8v vf0 = *(const half8v*)&Vt[0 * 2048 + (n * 16 + c15) * 32 + q * 8];
            half8v vf1 = *(const half8v*)&Vt[1 * 2048 + (n * 16 + c15) * 32 + q * 8];
            #pragma unroll
            for (int i = 0; i < 2; ++i) {
                O[i][n] = __builtin_amdgcn_mfma_f32_16x16x32_f16(pa[i][0], vf0, O[i][n], 0, 0, 0);
                O[i][n] = __builtin_amdgcn_mfma_f32_16x16x32_f16(pa[i][1], vf1, O[i][n], 0, 0, 0);
            }
        }
    }

    #pragma unroll
    for (int i = 0; i < 2; ++i)
        #pragma unroll
        for (int r = 0; r < 4; ++r) {
            float rl = 1.0f / li[i][r];
            int row = wrow0 + i * 16 + q * 4 + r;
            #pragma unroll
            for (int n = 0; n < 4; ++n)
                attn[((size_t)(b * Sc + row)) * Ec + h * HDc + n * 16 + c15] =
                    (h16)(O[i][n][r] * rl);
        }
}

// ---------------------------------------------------------------------------
extern "C" void kernel_launch(void* const* d_in, const int* in_sizes, int n_in,
                              void* d_out, int out_size, void* d_ws, size_t ws_size,
                              hipStream_t stream) {
    const float* x     = (const float*)d_in[0];
    const float* ln1_g = (const float*)d_in[1];
    const float* ln1_b = (const float*)d_in[2];
    const float* ln2_g = (const float*)d_in[3];
    const float* ln2_b = (const float*)d_in[4];
    const float* w_qkv = (const float*)d_in[5];
    const float* b_qkv = (const float*)d_in[6];
    const float* w_ao  = (const float*)d_in[7];
    const float* b_ao  = (const float*)d_in[8];
    const float* w_fc  = (const float*)d_in[9];
    const float* b_fc  = (const float*)d_in[10];
    const float* w_po  = (const float*)d_in[11];
    const float* b_po  = (const float*)d_in[12];
    float* out = (float*)d_out;

    // workspace (80 MB total):
    char* w = (char*)d_ws;
    h16* wqkv = (h16*)(w);             // 6 MB
    h16* wao  = (h16*)(w + 6291456);   // 2 MB
    h16* wfc  = (h16*)(w + 8388608);   // 8 MB
    h16* wpo  = (h16*)(w + 16777216);  // 8 MB
    h16* hb   = (h16*)(w + 25165824);  // 8 MB  (fp16 LN out, reused)
    h16* qkv  = (h16*)(w + 33554432);  // 24 MB
    h16* attn = (h16*)(w + 58720256);  // 8 MB
    float* x1 = (float*)(w + 67108864);// 16 MB
    h16* ff   = qkv;                   // 32 MB alias over qkv+attn (dead)

    dim3 blk(256);

    // weight converts fp32 -> fp16
    cvt_kernel<<<dim3(3 * Ec * Ec / 1024), blk, 0, stream>>>(w_qkv, wqkv, 3 * Ec * Ec);
    cvt_kernel<<<dim3(Ec * Ec / 1024), blk, 0, stream>>>(w_ao, wao, Ec * Ec);
    cvt_kernel<<<dim3(DFFc * Ec / 1024), blk, 0, stream>>>(w_fc, wfc, DFFc * Ec);
    cvt_kernel<<<dim3(Ec * DFFc / 1024), blk, 0, stream>>>(w_po, wpo, Ec * DFFc);

    // 1. hb = LN1(x)
    ln_kernel<<<dim3(ROWS), blk, 0, stream>>>(x, ln1_g, ln1_b, hb);
    // 2. qkv = hb @ w_qkv^T + b_qkv   (fp16 out)
    gemm_mfma<128, 0, h16><<<dim3(3 * Ec / 128, ROWS / 128), blk, 0, stream>>>(
        hb, wqkv, b_qkv, nullptr, qkv, ROWS, 3 * Ec, Ec);
    // 3. attn = causal_flash_attention(qkv)   (fp16 out)
    attn_mfma<<<dim3(Sc / 128, Bc * Hc), blk, 0, stream>>>(qkv, attn);
    // 4. x1 = x + attn @ w_ao^T + b_ao  (fp32)
    gemm_mfma<64, 1, float><<<dim3(Ec / 128, ROWS / 64), blk, 0, stream>>>(
        attn, wao, b_ao, x, x1, ROWS, Ec, Ec);
    // 5. hb = LN2(x1)
    ln_kernel<<<dim3(ROWS), blk, 0, stream>>>(x1, ln2_g, ln2_b, hb);
    // 6. ff = gelu(hb @ w_fc^T + b_fc)  (fp16)
    gemm_mfma<128, 2, h16><<<dim3(DFFc / 128, ROWS / 128), blk, 0, stream>>>(
        hb, wfc, b_fc, nullptr, ff, ROWS, DFFc, Ec);
    // 7. out = x1 + ff @ w_po^T + b_po  (fp32)
    gemm_mfma<64, 1, float><<<dim3(Ec / 128, ROWS / 64), blk, 0, stream>>>(
        ff, wpo, b_po, x1, out, ROWS, Ec, DFFc);
}

// Round 4
// 411.963 us; speedup vs baseline: 8.4500x; 1.1800x over previous
//
#include <hip/hip_runtime.h>
#include <cstddef>
#include <cstdint>

#define Bc 2
#define Sc 2048
#define Ec 1024
#define Hc 16
#define HDc 64
#define DFFc 4096
#define ROWS (Bc * Sc)  // 4096

typedef _Float16 half8v __attribute__((ext_vector_type(8)));  // 8 fp16 (4 VGPR)
typedef _Float16 half4v __attribute__((ext_vector_type(4)));
typedef float f32x4 __attribute__((ext_vector_type(4)));      // MFMA C/D frag
typedef _Float16 h16;

// async global->LDS, 16B per lane. LDS dest must be wave-uniform base + lane*16.
__device__ inline void gld_lds16(const void* g, void* l) {
    __builtin_amdgcn_global_load_lds(
        (const __attribute__((address_space(1))) void*)g,
        (__attribute__((address_space(3))) void*)l, 16, 0, 0);
}

__device__ inline float gelu_new(float x) {
    float x3 = x * x * x;
    return 0.5f * x * (1.0f + tanhf(0.7978845608028654f * (x + 0.044715f * x3)));
}

// ---------------------------------------------------------------------------
// fp32 -> fp16 convert (weights), n % 1024 == 0
// ---------------------------------------------------------------------------
__global__ __launch_bounds__(256) void cvt_kernel(const float* __restrict__ in,
                                                  h16* __restrict__ out, int n) {
    int i = (blockIdx.x * 256 + threadIdx.x) * 4;
    float4 v = *(const float4*)(in + i);
    half4v o;
    o.x = (h16)v.x; o.y = (h16)v.y; o.z = (h16)v.z; o.w = (h16)v.w;
    *(half4v*)(out + i) = o;
}

// ---------------------------------------------------------------------------
// LayerNorm: fp32 in, fp16 out. One block per row of E=1024.
// ---------------------------------------------------------------------------
__device__ inline float block_sum256(float v, float* sb) {
    #pragma unroll
    for (int o = 32; o > 0; o >>= 1) v += __shfl_down(v, o, 64);
    int lane = threadIdx.x & 63, w = threadIdx.x >> 6;
    if (lane == 0) sb[w] = v;
    __syncthreads();
    float r = sb[0] + sb[1] + sb[2] + sb[3];
    __syncthreads();
    return r;
}

__global__ __launch_bounds__(256) void ln_kernel(const float* __restrict__ x,
                                                 const float* __restrict__ g,
                                                 const float* __restrict__ b,
                                                 h16* __restrict__ out) {
    __shared__ float sb[4];
    int row = blockIdx.x;
    int t = threadIdx.x;
    const float* xr = x + (size_t)row * Ec;
    float4 v = ((const float4*)xr)[t];
    float s = v.x + v.y + v.z + v.w;
    float mu = block_sum256(s, sb) * (1.0f / Ec);
    float dx = v.x - mu, dy = v.y - mu, dz = v.z - mu, dw = v.w - mu;
    float ss = dx * dx + dy * dy + dz * dz + dw * dw;
    float var = block_sum256(ss, sb) * (1.0f / Ec);
    float inv = rsqrtf(var + 1e-5f);
    float4 gv = ((const float4*)g)[t];
    float4 bv = ((const float4*)b)[t];
    half4v o;
    o.x = (h16)(dx * inv * gv.x + bv.x);
    o.y = (h16)(dy * inv * gv.y + bv.y);
    o.z = (h16)(dz * inv * gv.z + bv.z);
    o.w = (h16)(dw * inv * gv.w + bv.w);
    ((half4v*)(out + (size_t)row * Ec))[t] = o;
}

// ---------------------------------------------------------------------------
// fp16 MFMA GEMM: C[M,N] = A[M,K] @ W[N,K]^T + bias (+epilogue)
// BN=128, BK=32, BM in {64,128}. 256 threads = 4 waves in 2x2.
// EPI: 0 none, 1 +R (fp32 resid), 2 gelu_new. OutT h16 or float.
// ---------------------------------------------------------------------------
template <int BM, int EPI, typename OutT>
__global__ __launch_bounds__(256) void gemm_mfma(
    const h16* __restrict__ A, const h16* __restrict__ W,
    const float* __restrict__ bias, const float* __restrict__ R,
    OutT* __restrict__ C, int M, int N, int K)
{
    constexpr int WM = BM / 2;   // wave row extent
    constexpr int MI = WM / 16;  // m-tiles per wave
    __shared__ h16 As[BM * 32];
    __shared__ h16 Ws[128 * 32];

    const int t = threadIdx.x;
    const int lane = t & 63, wv = t >> 6;
    const int wm = wv >> 1, wn = wv & 1;
    const int c15 = lane & 15, q = lane >> 4;
    const int row0 = blockIdx.y * BM, col0 = blockIdx.x * 128;
    const int arow = t >> 2, acol = (t & 3) << 3;  // staging row / col8

    f32x4 acc[MI][4];
    #pragma unroll
    for (int i = 0; i < MI; ++i)
        #pragma unroll
        for (int j = 0; j < 4; ++j)
            acc[i][j] = (f32x4){0.f, 0.f, 0.f, 0.f};

    for (int k0 = 0; k0 < K; k0 += 32) {
        __syncthreads();
        #pragma unroll
        for (int p = 0; p < BM / 64; ++p) {
            int r = p * 64 + arow;
            gld_lds16(A + (size_t)(row0 + r) * K + k0 + acol, &As[r * 32 + acol]);
        }
        #pragma unroll
        for (int p = 0; p < 2; ++p) {
            int r = p * 64 + arow;
            gld_lds16(W + (size_t)(col0 + r) * K + k0 + acol, &Ws[r * 32 + acol]);
        }
        __syncthreads();

        half8v af[MI], bf[4];
        #pragma unroll
        for (int i = 0; i < MI; ++i)
            af[i] = *(const half8v*)&As[(wm * WM + i * 16 + c15) * 32 + q * 8];
        #pragma unroll
        for (int j = 0; j < 4; ++j)
            bf[j] = *(const half8v*)&Ws[(wn * 64 + j * 16 + c15) * 32 + q * 8];
        #pragma unroll
        for (int i = 0; i < MI; ++i)
            #pragma unroll
            for (int j = 0; j < 4; ++j)
                acc[i][j] = __builtin_amdgcn_mfma_f32_16x16x32_f16(af[i], bf[j], acc[i][j], 0, 0, 0);
    }

    #pragma unroll
    for (int i = 0; i < MI; ++i) {
        #pragma unroll
        for (int j = 0; j < 4; ++j) {
            int col = col0 + wn * 64 + j * 16 + c15;
            float bv = bias[col];
            #pragma unroll
            for (int r = 0; r < 4; ++r) {
                int row = row0 + wm * WM + i * 16 + q * 4 + r;
                size_t off = (size_t)row * N + col;
                float v = acc[i][j][r] + bv;
                if (EPI == 1) v += R[off];
                if (EPI == 2) v = gelu_new(v);
                if (sizeof(OutT) == 2) ((h16*)C)[off] = (h16)v;
                else ((float*)C)[off] = v;
            }
        }
    }
}

// ---------------------------------------------------------------------------
// Causal flash attention v2, fp16 MFMA. qkv fp16 [B,S,H*192] (q|k|v per head).
// Grid: (16 pair-blocks, B*H). Block = 4 waves. Block handles q-tiles ja and
// 31-ja (64 rows each, wave = 16 rows of each) -> ~balanced work.
// S^T = K*Q^T trick: each lane owns whole queries -> 2-step shuffle reductions.
// Double-buffered K/V staging overlaps global->LDS with compute.
// ---------------------------------------------------------------------------
__global__ __launch_bounds__(256) void attn_mfma(const h16* __restrict__ qkv,
                                                 h16* __restrict__ attn) {
    __shared__ h16 Ks[2][2][64 * 32];   // [buf][d-half][key*32 + d]   16 KB
    __shared__ h16 Vt[2][2][64 * 32];   // [buf][key-half][d*32 + key] 16 KB
    __shared__ h16 Ps[4][2][16 * 72];   // [wave][i][query*72 + key]   18 KB

    const int t = threadIdx.x;
    const int lane = t & 63, wv = t >> 6;
    const int c15 = lane & 15, q = lane >> 4;
    const int bh = blockIdx.y, b = bh >> 4, h = bh & 15;
    const int ja = blockIdx.x;            // 0..15
    const int jb = 31 - ja;
    const int qa0 = ja * 64 + wv * 16;    // wave's 16-row base in tile a
    const int qb0 = jb * 64 + wv * 16;
    const int ktmax = 31 - ja;

    const int SE = 3 * Ec;
    const size_t hbase = (size_t)b * Sc * SE + (size_t)h * (3 * HDc);

    // Q fragments (register-resident)
    half8v qfa[2], qfb[2];
    #pragma unroll
    for (int kk = 0; kk < 2; ++kk) {
        qfa[kk] = *(const half8v*)(qkv + hbase + (size_t)(qa0 + c15) * SE + kk * 32 + q * 8);
        qfb[kk] = *(const half8v*)(qkv + hbase + (size_t)(qb0 + c15) * SE + kk * 32 + q * 8);
    }

    f32x4 O[2][4];
    #pragma unroll
    for (int i = 0; i < 2; ++i)
        #pragma unroll
        for (int n = 0; n < 4; ++n)
            O[i][n] = (f32x4){0.f, 0.f, 0.f, 0.f};
    float mi[2] = {-3e38f, -3e38f}, li[2] = {0.f, 0.f};

    const int krow = t >> 2, kjj = t & 3;          // K staging
    const int vkey = t & 31, vd0 = (t >> 5) << 3;  // V staging
    half8v vreg[2];

    // --- staging helpers ---
    auto stageK = [&](int kt, int bf) {
        #pragma unroll
        for (int p = 0; p < 2; ++p)
            gld_lds16(qkv + hbase + (size_t)(kt * 64 + krow) * SE + HDc + p * 32 + kjj * 8,
                      &Ks[bf][p][krow * 32 + kjj * 8]);
    };
    auto loadV = [&](int kt) {
        #pragma unroll
        for (int p = 0; p < 2; ++p)
            vreg[p] = *(const half8v*)(qkv + hbase +
                        (size_t)(kt * 64 + p * 32 + vkey) * SE + 2 * HDc + vd0);
    };
    auto scatV = [&](int bf) {
        #pragma unroll
        for (int p = 0; p < 2; ++p)
            #pragma unroll
            for (int u = 0; u < 8; ++u)
                Vt[bf][p][(vd0 + u) * 32 + vkey] = vreg[p][u];
    };

    stageK(0, 0); loadV(0); scatV(0);

    for (int kt = 0; kt <= ktmax; ++kt) {
        const int bf = kt & 1;
        __syncthreads();
        if (kt < ktmax) { stageK(kt + 1, bf ^ 1); loadV(kt + 1); }
        const int k0 = kt * 64;

        half8v kf[4][2];
        #pragma unroll
        for (int j = 0; j < 4; ++j)
            #pragma unroll
            for (int kk = 0; kk < 2; ++kk)
                kf[j][kk] = *(const half8v*)&Ks[bf][kk][(j * 16 + c15) * 32 + q * 8];

        #pragma unroll
        for (int i = 0; i < 2; ++i) {
            if (i == 0 && kt > ja) continue;   // tile_a fully masked (uniform)
            const half8v* qf = i ? qfb : qfa;
            const int qrow = (i ? qb0 : qa0) + c15;   // this lane's query

            // S^T tile: rows=keys (q*4+r per j), col=query (c15)
            f32x4 st[4];
            #pragma unroll
            for (int j = 0; j < 4; ++j) {
                f32x4 z = (f32x4){0.f, 0.f, 0.f, 0.f};
                z = __builtin_amdgcn_mfma_f32_16x16x32_f16(kf[j][0], qf[0], z, 0, 0, 0);
                st[j] = __builtin_amdgcn_mfma_f32_16x16x32_f16(kf[j][1], qf[1], st[j] = z, 0, 0, 0);
            }

            float sv[16];
            float mx = mi[i];
            #pragma unroll
            for (int j = 0; j < 4; ++j)
                #pragma unroll
                for (int r = 0; r < 4; ++r) {
                    int key = k0 + j * 16 + q * 4 + r;
                    float v = st[j][r] * 0.125f;
                    v = (key <= qrow) ? v : -3e38f;
                    sv[j * 4 + r] = v;
                    mx = fmaxf(mx, v);
                }
            mx = fmaxf(mx, __shfl_xor(mx, 16, 64));
            mx = fmaxf(mx, __shfl_xor(mx, 32, 64));
            float al = __expf(mi[i] - mx);
            mi[i] = mx;
            float ps = 0.f;
            #pragma unroll
            for (int j = 0; j < 4; ++j)
                #pragma unroll
                for (int r = 0; r < 4; ++r) {
                    float p = __expf(sv[j * 4 + r] - mx);
                    ps += p;
                    Ps[wv][i][c15 * 72 + j * 16 + q * 4 + r] = (h16)p;
                }
            ps += __shfl_xor(ps, 16, 64);
            ps += __shfl_xor(ps, 32, 64);
            li[i] = li[i] * al + ps;

            // broadcast alpha to C-layout rows, rescale O
            float alr[4];
            #pragma unroll
            for (int r = 0; r < 4; ++r) alr[r] = __shfl(al, q * 4 + r, 64);
            #pragma unroll
            for (int n = 0; n < 4; ++n)
                #pragma unroll
                for (int r = 0; r < 4; ++r) O[i][n][r] *= alr[r];

            // PV: A = P[query][key] (pad-72 rows), B = V^T[d][key]
            half8v pa0 = *(const half8v*)&Ps[wv][i][c15 * 72 + q * 8];
            half8v pa1 = *(const half8v*)&Ps[wv][i][c15 * 72 + 32 + q * 8];
            #pragma unroll
            for (int n = 0; n < 4; ++n) {
                half8v vf0 = *(const half8v*)&Vt[bf][0][(n * 16 + c15) * 32 + q * 8];
                half8v vf1 = *(const half8v*)&Vt[bf][1][(n * 16 + c15) * 32 + q * 8];
                O[i][n] = __builtin_amdgcn_mfma_f32_16x16x32_f16(pa0, vf0, O[i][n], 0, 0, 0);
                O[i][n] = __builtin_amdgcn_mfma_f32_16x16x32_f16(pa1, vf1, O[i][n], 0, 0, 0);
            }
        }
        if (kt < ktmax) scatV(bf ^ 1);
    }

    #pragma unroll
    for (int i = 0; i < 2; ++i) {
        int qb0i = i ? qb0 : qa0;
        float lr[4];
        #pragma unroll
        for (int r = 0; r < 4; ++r) lr[r] = __shfl(li[i], q * 4 + r, 64);
        #pragma unroll
        for (int r = 0; r < 4; ++r) {
            int row = qb0i + q * 4 + r;
            float rl = 1.0f / lr[r];
            #pragma unroll
            for (int n = 0; n < 4; ++n)
                attn[((size_t)(b * Sc + row)) * Ec + h * HDc + n * 16 + c15] =
                    (h16)(O[i][n][r] * rl);
        }
    }
}

// ---------------------------------------------------------------------------
extern "C" void kernel_launch(void* const* d_in, const int* in_sizes, int n_in,
                              void* d_out, int out_size, void* d_ws, size_t ws_size,
                              hipStream_t stream) {
    const float* x     = (const float*)d_in[0];
    const float* ln1_g = (const float*)d_in[1];
    const float* ln1_b = (const float*)d_in[2];
    const float* ln2_g = (const float*)d_in[3];
    const float* ln2_b = (const float*)d_in[4];
    const float* w_qkv = (const float*)d_in[5];
    const float* b_qkv = (const float*)d_in[6];
    const float* w_ao  = (const float*)d_in[7];
    const float* b_ao  = (const float*)d_in[8];
    const float* w_fc  = (const float*)d_in[9];
    const float* b_fc  = (const float*)d_in[10];
    const float* w_po  = (const float*)d_in[11];
    const float* b_po  = (const float*)d_in[12];
    float* out = (float*)d_out;

    // workspace (80 MB total):
    char* w = (char*)d_ws;
    h16* wqkv = (h16*)(w);             // 6 MB
    h16* wao  = (h16*)(w + 6291456);   // 2 MB
    h16* wfc  = (h16*)(w + 8388608);   // 8 MB
    h16* wpo  = (h16*)(w + 16777216);  // 8 MB
    h16* hb   = (h16*)(w + 25165824);  // 8 MB  (fp16 LN out, reused)
    h16* qkv  = (h16*)(w + 33554432);  // 24 MB
    h16* attn = (h16*)(w + 58720256);  // 8 MB
    float* x1 = (float*)(w + 67108864);// 16 MB
    h16* ff   = qkv;                   // 32 MB alias over qkv+attn (dead)

    dim3 blk(256);

    // weight converts fp32 -> fp16
    cvt_kernel<<<dim3(3 * Ec * Ec / 1024), blk, 0, stream>>>(w_qkv, wqkv, 3 * Ec * Ec);
    cvt_kernel<<<dim3(Ec * Ec / 1024), blk, 0, stream>>>(w_ao, wao, Ec * Ec);
    cvt_kernel<<<dim3(DFFc * Ec / 1024), blk, 0, stream>>>(w_fc, wfc, DFFc * Ec);
    cvt_kernel<<<dim3(Ec * DFFc / 1024), blk, 0, stream>>>(w_po, wpo, Ec * DFFc);

    // 1. hb = LN1(x)
    ln_kernel<<<dim3(ROWS), blk, 0, stream>>>(x, ln1_g, ln1_b, hb);
    // 2. qkv = hb @ w_qkv^T + b_qkv   (fp16 out)
    gemm_mfma<128, 0, h16><<<dim3(3 * Ec / 128, ROWS / 128), blk, 0, stream>>>(
        hb, wqkv, b_qkv, nullptr, qkv, ROWS, 3 * Ec, Ec);
    // 3. attn = causal_flash_attention(qkv)   (fp16 out)
    attn_mfma<<<dim3(16, Bc * Hc), blk, 0, stream>>>(qkv, attn);
    // 4. x1 = x + attn @ w_ao^T + b_ao  (fp32)
    gemm_mfma<64, 1, float><<<dim3(Ec / 128, ROWS / 64), blk, 0, stream>>>(
        attn, wao, b_ao, x, x1, ROWS, Ec, Ec);
    // 5. hb = LN2(x1)
    ln_kernel<<<dim3(ROWS), blk, 0, stream>>>(x1, ln2_g, ln2_b, hb);
    // 6. ff = gelu(hb @ w_fc^T + b_fc)  (fp16)
    gemm_mfma<128, 2, h16><<<dim3(DFFc / 128, ROWS / 128), blk, 0, stream>>>(
        hb, wfc, b_fc, nullptr, ff, ROWS, DFFc, Ec);
    // 7. out = x1 + ff @ w_po^T + b_po  (fp32)
    gemm_mfma<64, 1, float><<<dim3(Ec / 128, ROWS / 64), blk, 0, stream>>>(
        ff, wpo, b_po, x1, out, ROWS, Ec, DFFc);
}

// Round 5
// 391.238 us; speedup vs baseline: 8.8976x; 1.0530x over previous
//
#include <hip/hip_runtime.h>
#include <cstddef>
#include <cstdint>

#define Bc 2
#define Sc 2048
#define Ec 1024
#define Hc 16
#define HDc 64
#define DFFc 4096
#define ROWS (Bc * Sc)  // 4096

typedef _Float16 half8v __attribute__((ext_vector_type(8)));  // 8 fp16 (4 VGPR)
typedef _Float16 half4v __attribute__((ext_vector_type(4)));
typedef float f32x4 __attribute__((ext_vector_type(4)));      // MFMA C/D frag
typedef _Float16 h16;

// async global->LDS, 16B per lane. LDS dest must be wave-uniform base + lane*16.
__device__ inline void gld_lds16(const void* g, void* l) {
    __builtin_amdgcn_global_load_lds(
        (const __attribute__((address_space(1))) void*)g,
        (__attribute__((address_space(3))) void*)l, 16, 0, 0);
}

__device__ inline float gelu_new(float x) {
    float x3 = x * x * x;
    return 0.5f * x * (1.0f + tanhf(0.7978845608028654f * (x + 0.044715f * x3)));
}

// ---------------------------------------------------------------------------
// fp32 -> fp16 convert (weights), n % 1024 == 0
// ---------------------------------------------------------------------------
__global__ __launch_bounds__(256) void cvt_kernel(const float* __restrict__ in,
                                                  h16* __restrict__ out, int n) {
    int i = (blockIdx.x * 256 + threadIdx.x) * 4;
    float4 v = *(const float4*)(in + i);
    half4v o;
    o.x = (h16)v.x; o.y = (h16)v.y; o.z = (h16)v.z; o.w = (h16)v.w;
    *(half4v*)(out + i) = o;
}

// ---------------------------------------------------------------------------
// LayerNorm: fp32 in, fp16 out. One block per row of E=1024.
// ---------------------------------------------------------------------------
__device__ inline float block_sum256(float v, float* sb) {
    #pragma unroll
    for (int o = 32; o > 0; o >>= 1) v += __shfl_down(v, o, 64);
    int lane = threadIdx.x & 63, w = threadIdx.x >> 6;
    if (lane == 0) sb[w] = v;
    __syncthreads();
    float r = sb[0] + sb[1] + sb[2] + sb[3];
    __syncthreads();
    return r;
}

__global__ __launch_bounds__(256) void ln_kernel(const float* __restrict__ x,
                                                 const float* __restrict__ g,
                                                 const float* __restrict__ b,
                                                 h16* __restrict__ out) {
    __shared__ float sb[4];
    int row = blockIdx.x;
    int t = threadIdx.x;
    const float* xr = x + (size_t)row * Ec;
    float4 v = ((const float4*)xr)[t];
    float s = v.x + v.y + v.z + v.w;
    float mu = block_sum256(s, sb) * (1.0f / Ec);
    float dx = v.x - mu, dy = v.y - mu, dz = v.z - mu, dw = v.w - mu;
    float ss = dx * dx + dy * dy + dz * dz + dw * dw;
    float var = block_sum256(ss, sb) * (1.0f / Ec);
    float inv = rsqrtf(var + 1e-5f);
    float4 gv = ((const float4*)g)[t];
    float4 bv = ((const float4*)b)[t];
    half4v o;
    o.x = (h16)(dx * inv * gv.x + bv.x);
    o.y = (h16)(dy * inv * gv.y + bv.y);
    o.z = (h16)(dz * inv * gv.z + bv.z);
    o.w = (h16)(dw * inv * gv.w + bv.w);
    ((half4v*)(out + (size_t)row * Ec))[t] = o;
}

// ---------------------------------------------------------------------------
// fp16 MFMA GEMM (big tile): C[M,N] = A[M,K] @ W[N,K]^T + bias (+epilogue)
// BM=BN=128, BK=32, 256 threads = 4 waves in 2x2. 16 MFMA/wave/barrier.
// EPI: 0 none, 1 +R (fp32 resid), 2 gelu_new. OutT h16 or float.
// ---------------------------------------------------------------------------
template <int EPI, typename OutT>
__global__ __launch_bounds__(256) void gemm_mfma(
    const h16* __restrict__ A, const h16* __restrict__ W,
    const float* __restrict__ bias, const float* __restrict__ R,
    OutT* __restrict__ C, int M, int N, int K)
{
    __shared__ h16 As[128 * 32];
    __shared__ h16 Ws[128 * 32];

    const int t = threadIdx.x;
    const int lane = t & 63, wv = t >> 6;
    const int wm = wv >> 1, wn = wv & 1;
    const int c15 = lane & 15, q = lane >> 4;
    const int row0 = blockIdx.y * 128, col0 = blockIdx.x * 128;
    const int arow = t >> 2, acol = (t & 3) << 3;  // staging row / col8

    f32x4 acc[4][4];
    #pragma unroll
    for (int i = 0; i < 4; ++i)
        #pragma unroll
        for (int j = 0; j < 4; ++j)
            acc[i][j] = (f32x4){0.f, 0.f, 0.f, 0.f};

    for (int k0 = 0; k0 < K; k0 += 32) {
        __syncthreads();
        #pragma unroll
        for (int p = 0; p < 2; ++p) {
            int r = p * 64 + arow;
            gld_lds16(A + (size_t)(row0 + r) * K + k0 + acol, &As[r * 32 + acol]);
            gld_lds16(W + (size_t)(col0 + r) * K + k0 + acol, &Ws[r * 32 + acol]);
        }
        __syncthreads();

        half8v af[4], bf[4];
        #pragma unroll
        for (int i = 0; i < 4; ++i)
            af[i] = *(const half8v*)&As[(wm * 64 + i * 16 + c15) * 32 + q * 8];
        #pragma unroll
        for (int j = 0; j < 4; ++j)
            bf[j] = *(const half8v*)&Ws[(wn * 64 + j * 16 + c15) * 32 + q * 8];
        #pragma unroll
        for (int i = 0; i < 4; ++i)
            #pragma unroll
            for (int j = 0; j < 4; ++j)
                acc[i][j] = __builtin_amdgcn_mfma_f32_16x16x32_f16(af[i], bf[j], acc[i][j], 0, 0, 0);
    }

    #pragma unroll
    for (int i = 0; i < 4; ++i) {
        #pragma unroll
        for (int j = 0; j < 4; ++j) {
            int col = col0 + wn * 64 + j * 16 + c15;
            float bv = bias[col];
            #pragma unroll
            for (int r = 0; r < 4; ++r) {
                int row = row0 + wm * 64 + i * 16 + q * 4 + r;
                size_t off = (size_t)row * N + col;
                float v = acc[i][j][r] + bv;
                if (EPI == 1) v += R[off];
                if (EPI == 2) v = gelu_new(v);
                if (sizeof(OutT) == 2) ((h16*)C)[off] = (h16)v;
                else ((float*)C)[off] = v;
            }
        }
    }
}

// ---------------------------------------------------------------------------
// fp16 MFMA GEMM (skinny-N, deep-K): BM=64, BN=128, BK=64 as 2 x BK32 buffers
// so each sub-buffer keeps the proven 64B-row-stride (conflict-free) layout.
// 256 threads = 4 waves in 2x2; 16 MFMA/wave/barrier. For AO / PO (N=1024).
// ---------------------------------------------------------------------------
template <int EPI, typename OutT>
__global__ __launch_bounds__(256) void gemm_k64(
    const h16* __restrict__ A, const h16* __restrict__ W,
    const float* __restrict__ bias, const float* __restrict__ R,
    OutT* __restrict__ C, int M, int N, int K)
{
    __shared__ h16 As[2][64 * 32];    // 8 KB
    __shared__ h16 Ws[2][128 * 32];   // 16 KB

    const int t = threadIdx.x;
    const int lane = t & 63, wv = t >> 6;
    const int wm = wv >> 1, wn = wv & 1;   // wave tile: rows wm*32, cols wn*64
    const int c15 = lane & 15, q = lane >> 4;
    const int row0 = blockIdx.y * 64, col0 = blockIdx.x * 128;
    const int arow = t >> 2, acol = (t & 3) << 3;

    f32x4 acc[2][4];
    #pragma unroll
    for (int i = 0; i < 2; ++i)
        #pragma unroll
        for (int j = 0; j < 4; ++j)
            acc[i][j] = (f32x4){0.f, 0.f, 0.f, 0.f};

    for (int k0 = 0; k0 < K; k0 += 64) {
        __syncthreads();
        #pragma unroll
        for (int kk = 0; kk < 2; ++kk) {
            gld_lds16(A + (size_t)(row0 + arow) * K + k0 + kk * 32 + acol,
                      &As[kk][arow * 32 + acol]);
            #pragma unroll
            for (int p = 0; p < 2; ++p) {
                int r = p * 64 + arow;
                gld_lds16(W + (size_t)(col0 + r) * K + k0 + kk * 32 + acol,
                          &Ws[kk][r * 32 + acol]);
            }
        }
        __syncthreads();

        #pragma unroll
        for (int kk = 0; kk < 2; ++kk) {
            half8v af[2], bf[4];
            #pragma unroll
            for (int i = 0; i < 2; ++i)
                af[i] = *(const half8v*)&As[kk][(wm * 32 + i * 16 + c15) * 32 + q * 8];
            #pragma unroll
            for (int j = 0; j < 4; ++j)
                bf[j] = *(const half8v*)&Ws[kk][(wn * 64 + j * 16 + c15) * 32 + q * 8];
            #pragma unroll
            for (int i = 0; i < 2; ++i)
                #pragma unroll
                for (int j = 0; j < 4; ++j)
                    acc[i][j] = __builtin_amdgcn_mfma_f32_16x16x32_f16(af[i], bf[j], acc[i][j], 0, 0, 0);
        }
    }

    #pragma unroll
    for (int i = 0; i < 2; ++i) {
        #pragma unroll
        for (int j = 0; j < 4; ++j) {
            int col = col0 + wn * 64 + j * 16 + c15;
            float bv = bias[col];
            #pragma unroll
            for (int r = 0; r < 4; ++r) {
                int row = row0 + wm * 32 + i * 16 + q * 4 + r;
                size_t off = (size_t)row * N + col;
                float v = acc[i][j][r] + bv;
                if (EPI == 1) v += R[off];
                if (EPI == 2) v = gelu_new(v);
                if (sizeof(OutT) == 2) ((h16*)C)[off] = (h16)v;
                else ((float*)C)[off] = v;
            }
        }
    }
}

// ---------------------------------------------------------------------------
// Causal flash attention v2, fp16 MFMA. qkv fp16 [B,S,H*192] (q|k|v per head).
// Grid: (16 pair-blocks, B*H). Block = 4 waves. Block handles q-tiles ja and
// 31-ja (64 rows each, wave = 16 rows of each) -> ~balanced work.
// S^T = K*Q^T trick: each lane owns whole queries -> 2-step shuffle reductions.
// Double-buffered K/V staging overlaps global->LDS with compute.
// ---------------------------------------------------------------------------
__global__ __launch_bounds__(256) void attn_mfma(const h16* __restrict__ qkv,
                                                 h16* __restrict__ attn) {
    __shared__ h16 Ks[2][2][64 * 32];   // [buf][d-half][key*32 + d]   16 KB
    __shared__ h16 Vt[2][2][64 * 32];   // [buf][key-half][d*32 + key] 16 KB
    __shared__ h16 Ps[4][2][16 * 72];   // [wave][i][query*72 + key]   18 KB

    const int t = threadIdx.x;
    const int lane = t & 63, wv = t >> 6;
    const int c15 = lane & 15, q = lane >> 4;
    const int bh = blockIdx.y, b = bh >> 4, h = bh & 15;
    const int ja = blockIdx.x;            // 0..15
    const int jb = 31 - ja;
    const int qa0 = ja * 64 + wv * 16;    // wave's 16-row base in tile a
    const int qb0 = jb * 64 + wv * 16;
    const int ktmax = 31 - ja;

    const int SE = 3 * Ec;
    const size_t hbase = (size_t)b * Sc * SE + (size_t)h * (3 * HDc);

    // Q fragments (register-resident)
    half8v qfa[2], qfb[2];
    #pragma unroll
    for (int kk = 0; kk < 2; ++kk) {
        qfa[kk] = *(const half8v*)(qkv + hbase + (size_t)(qa0 + c15) * SE + kk * 32 + q * 8);
        qfb[kk] = *(const half8v*)(qkv + hbase + (size_t)(qb0 + c15) * SE + kk * 32 + q * 8);
    }

    f32x4 O[2][4];
    #pragma unroll
    for (int i = 0; i < 2; ++i)
        #pragma unroll
        for (int n = 0; n < 4; ++n)
            O[i][n] = (f32x4){0.f, 0.f, 0.f, 0.f};
    float mi[2] = {-3e38f, -3e38f}, li[2] = {0.f, 0.f};

    const int krow = t >> 2, kjj = t & 3;          // K staging
    const int vkey = t & 31, vd0 = (t >> 5) << 3;  // V staging
    half8v vreg[2];

    // --- staging helpers ---
    auto stageK = [&](int kt, int bf) {
        #pragma unroll
        for (int p = 0; p < 2; ++p)
            gld_lds16(qkv + hbase + (size_t)(kt * 64 + krow) * SE + HDc + p * 32 + kjj * 8,
                      &Ks[bf][p][krow * 32 + kjj * 8]);
    };
    auto loadV = [&](int kt) {
        #pragma unroll
        for (int p = 0; p < 2; ++p)
            vreg[p] = *(const half8v*)(qkv + hbase +
                        (size_t)(kt * 64 + p * 32 + vkey) * SE + 2 * HDc + vd0);
    };
    auto scatV = [&](int bf) {
        #pragma unroll
        for (int p = 0; p < 2; ++p)
            #pragma unroll
            for (int u = 0; u < 8; ++u)
                Vt[bf][p][(vd0 + u) * 32 + vkey] = vreg[p][u];
    };

    stageK(0, 0); loadV(0); scatV(0);

    for (int kt = 0; kt <= ktmax; ++kt) {
        const int bf = kt & 1;
        __syncthreads();
        if (kt < ktmax) { stageK(kt + 1, bf ^ 1); loadV(kt + 1); }
        const int k0 = kt * 64;

        half8v kf[4][2];
        #pragma unroll
        for (int j = 0; j < 4; ++j)
            #pragma unroll
            for (int kk = 0; kk < 2; ++kk)
                kf[j][kk] = *(const half8v*)&Ks[bf][kk][(j * 16 + c15) * 32 + q * 8];

        #pragma unroll
        for (int i = 0; i < 2; ++i) {
            if (i == 0 && kt > ja) continue;   // tile_a fully masked (uniform)
            const half8v* qf = i ? qfb : qfa;
            const int qrow = (i ? qb0 : qa0) + c15;   // this lane's query

            // S^T tile: rows=keys (q*4+r per j), col=query (c15)
            f32x4 st[4];
            #pragma unroll
            for (int j = 0; j < 4; ++j) {
                f32x4 z = (f32x4){0.f, 0.f, 0.f, 0.f};
                z = __builtin_amdgcn_mfma_f32_16x16x32_f16(kf[j][0], qf[0], z, 0, 0, 0);
                st[j] = __builtin_amdgcn_mfma_f32_16x16x32_f16(kf[j][1], qf[1], st[j] = z, 0, 0, 0);
            }

            float sv[16];
            float mx = mi[i];
            #pragma unroll
            for (int j = 0; j < 4; ++j)
                #pragma unroll
                for (int r = 0; r < 4; ++r) {
                    int key = k0 + j * 16 + q * 4 + r;
                    float v = st[j][r] * 0.125f;
                    v = (key <= qrow) ? v : -3e38f;
                    sv[j * 4 + r] = v;
                    mx = fmaxf(mx, v);
                }
            mx = fmaxf(mx, __shfl_xor(mx, 16, 64));
            mx = fmaxf(mx, __shfl_xor(mx, 32, 64));
            float al = __expf(mi[i] - mx);
            mi[i] = mx;
            float ps = 0.f;
            #pragma unroll
            for (int j = 0; j < 4; ++j)
                #pragma unroll
                for (int r = 0; r < 4; ++r) {
                    float p = __expf(sv[j * 4 + r] - mx);
                    ps += p;
                    Ps[wv][i][c15 * 72 + j * 16 + q * 4 + r] = (h16)p;
                }
            ps += __shfl_xor(ps, 16, 64);
            ps += __shfl_xor(ps, 32, 64);
            li[i] = li[i] * al + ps;

            // broadcast alpha to C-layout rows, rescale O
            float alr[4];
            #pragma unroll
            for (int r = 0; r < 4; ++r) alr[r] = __shfl(al, q * 4 + r, 64);
            #pragma unroll
            for (int n = 0; n < 4; ++n)
                #pragma unroll
                for (int r = 0; r < 4; ++r) O[i][n][r] *= alr[r];

            // PV: A = P[query][key] (pad-72 rows), B = V^T[d][key]
            half8v pa0 = *(const half8v*)&Ps[wv][i][c15 * 72 + q * 8];
            half8v pa1 = *(const half8v*)&Ps[wv][i][c15 * 72 + 32 + q * 8];
            #pragma unroll
            for (int n = 0; n < 4; ++n) {
                half8v vf0 = *(const half8v*)&Vt[bf][0][(n * 16 + c15) * 32 + q * 8];
                half8v vf1 = *(const half8v*)&Vt[bf][1][(n * 16 + c15) * 32 + q * 8];
                O[i][n] = __builtin_amdgcn_mfma_f32_16x16x32_f16(pa0, vf0, O[i][n], 0, 0, 0);
                O[i][n] = __builtin_amdgcn_mfma_f32_16x16x32_f16(pa1, vf1, O[i][n], 0, 0, 0);
            }
        }
        if (kt < ktmax) scatV(bf ^ 1);
    }

    #pragma unroll
    for (int i = 0; i < 2; ++i) {
        int qb0i = i ? qb0 : qa0;
        float lr[4];
        #pragma unroll
        for (int r = 0; r < 4; ++r) lr[r] = __shfl(li[i], q * 4 + r, 64);
        #pragma unroll
        for (int r = 0; r < 4; ++r) {
            int row = qb0i + q * 4 + r;
            float rl = 1.0f / lr[r];
            #pragma unroll
            for (int n = 0; n < 4; ++n)
                attn[((size_t)(b * Sc + row)) * Ec + h * HDc + n * 16 + c15] =
                    (h16)(O[i][n][r] * rl);
        }
    }
}

// ---------------------------------------------------------------------------
extern "C" void kernel_launch(void* const* d_in, const int* in_sizes, int n_in,
                              void* d_out, int out_size, void* d_ws, size_t ws_size,
                              hipStream_t stream) {
    const float* x     = (const float*)d_in[0];
    const float* ln1_g = (const float*)d_in[1];
    const float* ln1_b = (const float*)d_in[2];
    const float* ln2_g = (const float*)d_in[3];
    const float* ln2_b = (const float*)d_in[4];
    const float* w_qkv = (const float*)d_in[5];
    const float* b_qkv = (const float*)d_in[6];
    const float* w_ao  = (const float*)d_in[7];
    const float* b_ao  = (const float*)d_in[8];
    const float* w_fc  = (const float*)d_in[9];
    const float* b_fc  = (const float*)d_in[10];
    const float* w_po  = (const float*)d_in[11];
    const float* b_po  = (const float*)d_in[12];
    float* out = (float*)d_out;

    // workspace (80 MB total):
    char* w = (char*)d_ws;
    h16* wqkv = (h16*)(w);             // 6 MB
    h16* wao  = (h16*)(w + 6291456);   // 2 MB
    h16* wfc  = (h16*)(w + 8388608);   // 8 MB
    h16* wpo  = (h16*)(w + 16777216);  // 8 MB
    h16* hb   = (h16*)(w + 25165824);  // 8 MB  (fp16 LN out, reused)
    h16* qkv  = (h16*)(w + 33554432);  // 24 MB
    h16* attn = (h16*)(w + 58720256);  // 8 MB
    float* x1 = (float*)(w + 67108864);// 16 MB
    h16* ff   = qkv;                   // 32 MB alias over qkv+attn (dead)

    dim3 blk(256);

    // weight converts fp32 -> fp16
    cvt_kernel<<<dim3(3 * Ec * Ec / 1024), blk, 0, stream>>>(w_qkv, wqkv, 3 * Ec * Ec);
    cvt_kernel<<<dim3(Ec * Ec / 1024), blk, 0, stream>>>(w_ao, wao, Ec * Ec);
    cvt_kernel<<<dim3(DFFc * Ec / 1024), blk, 0, stream>>>(w_fc, wfc, DFFc * Ec);
    cvt_kernel<<<dim3(Ec * DFFc / 1024), blk, 0, stream>>>(w_po, wpo, Ec * DFFc);

    // 1. hb = LN1(x)
    ln_kernel<<<dim3(ROWS), blk, 0, stream>>>(x, ln1_g, ln1_b, hb);
    // 2. qkv = hb @ w_qkv^T + b_qkv   (fp16 out)
    gemm_mfma<0, h16><<<dim3(3 * Ec / 128, ROWS / 128), blk, 0, stream>>>(
        hb, wqkv, b_qkv, nullptr, qkv, ROWS, 3 * Ec, Ec);
    // 3. attn = causal_flash_attention(qkv)   (fp16 out)
    attn_mfma<<<dim3(16, Bc * Hc), blk, 0, stream>>>(qkv, attn);
    // 4. x1 = x + attn @ w_ao^T + b_ao  (fp32)  [skinny-N deep-K kernel]
    gemm_k64<1, float><<<dim3(Ec / 128, ROWS / 64), blk, 0, stream>>>(
        attn, wao, b_ao, x, x1, ROWS, Ec, Ec);
    // 5. hb = LN2(x1)
    ln_kernel<<<dim3(ROWS), blk, 0, stream>>>(x1, ln2_g, ln2_b, hb);
    // 6. ff = gelu(hb @ w_fc^T + b_fc)  (fp16)
    gemm_mfma<2, h16><<<dim3(DFFc / 128, ROWS / 128), blk, 0, stream>>>(
        hb, wfc, b_fc, nullptr, ff, ROWS, DFFc, Ec);
    // 7. out = x1 + ff @ w_po^T + b_po  (fp32)  [skinny-N deep-K kernel]
    gemm_k64<1, float><<<dim3(Ec / 128, ROWS / 64), blk, 0, stream>>>(
        ff, wpo, b_po, x1, out, ROWS, Ec, DFFc);
}

// Round 6
// 379.902 us; speedup vs baseline: 9.1631x; 1.0298x over previous
//
#include <hip/hip_runtime.h>
#include <cstddef>
#include <cstdint>

#define Bc 2
#define Sc 2048
#define Ec 1024
#define Hc 16
#define HDc 64
#define DFFc 4096
#define ROWS (Bc * Sc)  // 4096

typedef _Float16 half8v __attribute__((ext_vector_type(8)));  // 8 fp16 (4 VGPR)
typedef _Float16 half4v __attribute__((ext_vector_type(4)));
typedef float f32x4 __attribute__((ext_vector_type(4)));      // MFMA C/D frag
typedef _Float16 h16;

// async global->LDS, 16B per lane. LDS dest must be wave-uniform base + lane*16.
__device__ inline void gld_lds16(const void* g, void* l) {
    __builtin_amdgcn_global_load_lds(
        (const __attribute__((address_space(1))) void*)g,
        (__attribute__((address_space(3))) void*)l, 16, 0, 0);
}

// gelu_new via sigmoid identity: 0.5x(1+tanh(z)) == x*sigmoid(2z).
// One v_exp_f32 + rcp instead of libm tanhf.
__device__ inline float gelu_new(float x) {
    float u = 1.5957691216057308f * fmaf(0.044715f * x * x, x, x);
    return x / (1.0f + __expf(-u));
}

// ---------------------------------------------------------------------------
// fp32 -> fp16 convert (weights), n % 1024 == 0
// ---------------------------------------------------------------------------
__global__ __launch_bounds__(256) void cvt_kernel(const float* __restrict__ in,
                                                  h16* __restrict__ out, int n) {
    int i = (blockIdx.x * 256 + threadIdx.x) * 4;
    float4 v = *(const float4*)(in + i);
    half4v o;
    o.x = (h16)v.x; o.y = (h16)v.y; o.z = (h16)v.z; o.w = (h16)v.w;
    *(half4v*)(out + i) = o;
}

// ---------------------------------------------------------------------------
// LayerNorm: fp32 in, fp16 out. One block per row of E=1024.
// ---------------------------------------------------------------------------
__device__ inline float block_sum256(float v, float* sb) {
    #pragma unroll
    for (int o = 32; o > 0; o >>= 1) v += __shfl_down(v, o, 64);
    int lane = threadIdx.x & 63, w = threadIdx.x >> 6;
    if (lane == 0) sb[w] = v;
    __syncthreads();
    float r = sb[0] + sb[1] + sb[2] + sb[3];
    __syncthreads();
    return r;
}

__global__ __launch_bounds__(256) void ln_kernel(const float* __restrict__ x,
                                                 const float* __restrict__ g,
                                                 const float* __restrict__ b,
                                                 h16* __restrict__ out) {
    __shared__ float sb[4];
    int row = blockIdx.x;
    int t = threadIdx.x;
    const float* xr = x + (size_t)row * Ec;
    float4 v = ((const float4*)xr)[t];
    float s = v.x + v.y + v.z + v.w;
    float mu = block_sum256(s, sb) * (1.0f / Ec);
    float dx = v.x - mu, dy = v.y - mu, dz = v.z - mu, dw = v.w - mu;
    float ss = dx * dx + dy * dy + dz * dz + dw * dw;
    float var = block_sum256(ss, sb) * (1.0f / Ec);
    float inv = rsqrtf(var + 1e-5f);
    float4 gv = ((const float4*)g)[t];
    float4 bv = ((const float4*)b)[t];
    half4v o;
    o.x = (h16)(dx * inv * gv.x + bv.x);
    o.y = (h16)(dy * inv * gv.y + bv.y);
    o.z = (h16)(dz * inv * gv.z + bv.z);
    o.w = (h16)(dw * inv * gv.w + bv.w);
    ((half4v*)(out + (size_t)row * Ec))[t] = o;
}

// ---------------------------------------------------------------------------
// fp16 MFMA GEMM (big tile): C[M,N] = A[M,K] @ W[N,K]^T + bias (+epilogue)
// BM=BN=128, BK=64 as 2 x BK32 sub-buffers (keeps 64B-row-stride layout).
// 256 threads = 4 waves in 2x2; 32 MFMA/wave/barrier.
// EPI: 0 none, 1 +R (fp32 resid), 2 gelu_new. OutT h16 or float.
// ---------------------------------------------------------------------------
template <int EPI, typename OutT>
__global__ __launch_bounds__(256) void gemm_mfma(
    const h16* __restrict__ A, const h16* __restrict__ W,
    const float* __restrict__ bias, const float* __restrict__ R,
    OutT* __restrict__ C, int M, int N, int K)
{
    __shared__ h16 As[2][128 * 32];   // 16 KB
    __shared__ h16 Ws[2][128 * 32];   // 16 KB

    const int t = threadIdx.x;
    const int lane = t & 63, wv = t >> 6;
    const int wm = wv >> 1, wn = wv & 1;
    const int c15 = lane & 15, q = lane >> 4;
    const int row0 = blockIdx.y * 128, col0 = blockIdx.x * 128;
    const int arow = t >> 2, acol = (t & 3) << 3;  // staging row / col8

    f32x4 acc[4][4];
    #pragma unroll
    for (int i = 0; i < 4; ++i)
        #pragma unroll
        for (int j = 0; j < 4; ++j)
            acc[i][j] = (f32x4){0.f, 0.f, 0.f, 0.f};

    for (int k0 = 0; k0 < K; k0 += 64) {
        __syncthreads();
        #pragma unroll
        for (int kk = 0; kk < 2; ++kk)
            #pragma unroll
            for (int p = 0; p < 2; ++p) {
                int r = p * 64 + arow;
                gld_lds16(A + (size_t)(row0 + r) * K + k0 + kk * 32 + acol,
                          &As[kk][r * 32 + acol]);
                gld_lds16(W + (size_t)(col0 + r) * K + k0 + kk * 32 + acol,
                          &Ws[kk][r * 32 + acol]);
            }
        __syncthreads();

        #pragma unroll
        for (int kk = 0; kk < 2; ++kk) {
            half8v af[4], bf[4];
            #pragma unroll
            for (int i = 0; i < 4; ++i)
                af[i] = *(const half8v*)&As[kk][(wm * 64 + i * 16 + c15) * 32 + q * 8];
            #pragma unroll
            for (int j = 0; j < 4; ++j)
                bf[j] = *(const half8v*)&Ws[kk][(wn * 64 + j * 16 + c15) * 32 + q * 8];
            #pragma unroll
            for (int i = 0; i < 4; ++i)
                #pragma unroll
                for (int j = 0; j < 4; ++j)
                    acc[i][j] = __builtin_amdgcn_mfma_f32_16x16x32_f16(af[i], bf[j], acc[i][j], 0, 0, 0);
        }
    }

    #pragma unroll
    for (int i = 0; i < 4; ++i) {
        #pragma unroll
        for (int j = 0; j < 4; ++j) {
            int col = col0 + wn * 64 + j * 16 + c15;
            float bv = bias[col];
            #pragma unroll
            for (int r = 0; r < 4; ++r) {
                int row = row0 + wm * 64 + i * 16 + q * 4 + r;
                size_t off = (size_t)row * N + col;
                float v = acc[i][j][r] + bv;
                if (EPI == 1) v += R[off];
                if (EPI == 2) v = gelu_new(v);
                if (sizeof(OutT) == 2) ((h16*)C)[off] = (h16)v;
                else ((float*)C)[off] = v;
            }
        }
    }
}

// ---------------------------------------------------------------------------
// fp16 MFMA GEMM (skinny-N, deep-K): BM=64, BN=128, BK=64 as 2 x BK32 buffers
// so each sub-buffer keeps the proven 64B-row-stride (conflict-free) layout.
// 256 threads = 4 waves in 2x2; 16 MFMA/wave/barrier. For AO / PO (N=1024).
// ---------------------------------------------------------------------------
template <int EPI, typename OutT>
__global__ __launch_bounds__(256) void gemm_k64(
    const h16* __restrict__ A, const h16* __restrict__ W,
    const float* __restrict__ bias, const float* __restrict__ R,
    OutT* __restrict__ C, int M, int N, int K)
{
    __shared__ h16 As[2][64 * 32];    // 8 KB
    __shared__ h16 Ws[2][128 * 32];   // 16 KB

    const int t = threadIdx.x;
    const int lane = t & 63, wv = t >> 6;
    const int wm = wv >> 1, wn = wv & 1;   // wave tile: rows wm*32, cols wn*64
    const int c15 = lane & 15, q = lane >> 4;
    const int row0 = blockIdx.y * 64, col0 = blockIdx.x * 128;
    const int arow = t >> 2, acol = (t & 3) << 3;

    f32x4 acc[2][4];
    #pragma unroll
    for (int i = 0; i < 2; ++i)
        #pragma unroll
        for (int j = 0; j < 4; ++j)
            acc[i][j] = (f32x4){0.f, 0.f, 0.f, 0.f};

    for (int k0 = 0; k0 < K; k0 += 64) {
        __syncthreads();
        #pragma unroll
        for (int kk = 0; kk < 2; ++kk) {
            gld_lds16(A + (size_t)(row0 + arow) * K + k0 + kk * 32 + acol,
                      &As[kk][arow * 32 + acol]);
            #pragma unroll
            for (int p = 0; p < 2; ++p) {
                int r = p * 64 + arow;
                gld_lds16(W + (size_t)(col0 + r) * K + k0 + kk * 32 + acol,
                          &Ws[kk][r * 32 + acol]);
            }
        }
        __syncthreads();

        #pragma unroll
        for (int kk = 0; kk < 2; ++kk) {
            half8v af[2], bf[4];
            #pragma unroll
            for (int i = 0; i < 2; ++i)
                af[i] = *(const half8v*)&As[kk][(wm * 32 + i * 16 + c15) * 32 + q * 8];
            #pragma unroll
            for (int j = 0; j < 4; ++j)
                bf[j] = *(const half8v*)&Ws[kk][(wn * 64 + j * 16 + c15) * 32 + q * 8];
            #pragma unroll
            for (int i = 0; i < 2; ++i)
                #pragma unroll
                for (int j = 0; j < 4; ++j)
                    acc[i][j] = __builtin_amdgcn_mfma_f32_16x16x32_f16(af[i], bf[j], acc[i][j], 0, 0, 0);
        }
    }

    #pragma unroll
    for (int i = 0; i < 2; ++i) {
        #pragma unroll
        for (int j = 0; j < 4; ++j) {
            int col = col0 + wn * 64 + j * 16 + c15;
            float bv = bias[col];
            #pragma unroll
            for (int r = 0; r < 4; ++r) {
                int row = row0 + wm * 32 + i * 16 + q * 4 + r;
                size_t off = (size_t)row * N + col;
                float v = acc[i][j][r] + bv;
                if (EPI == 1) v += R[off];
                if (EPI == 2) v = gelu_new(v);
                if (sizeof(OutT) == 2) ((h16*)C)[off] = (h16)v;
                else ((float*)C)[off] = v;
            }
        }
    }
}

// ---------------------------------------------------------------------------
// Causal flash attention v2, fp16 MFMA. qkv fp16 [B,S,H*192] (q|k|v per head).
// Grid: (16 pair-blocks, B*H). Block = 4 waves. Block handles q-tiles ja and
// 31-ja (64 rows each, wave = 16 rows of each) -> ~balanced work.
// S^T = K*Q^T trick: each lane owns whole queries -> 2-step shuffle reductions.
// Double-buffered K/V staging overlaps global->LDS with compute.
// ---------------------------------------------------------------------------
__global__ __launch_bounds__(256) void attn_mfma(const h16* __restrict__ qkv,
                                                 h16* __restrict__ attn) {
    __shared__ h16 Ks[2][2][64 * 32];   // [buf][d-half][key*32 + d]   16 KB
    __shared__ h16 Vt[2][2][64 * 32];   // [buf][key-half][d*32 + key] 16 KB
    __shared__ h16 Ps[4][2][16 * 72];   // [wave][i][query*72 + key]   18 KB

    const int t = threadIdx.x;
    const int lane = t & 63, wv = t >> 6;
    const int c15 = lane & 15, q = lane >> 4;
    const int bh = blockIdx.y, b = bh >> 4, h = bh & 15;
    const int ja = blockIdx.x;            // 0..15
    const int jb = 31 - ja;
    const int qa0 = ja * 64 + wv * 16;    // wave's 16-row base in tile a
    const int qb0 = jb * 64 + wv * 16;
    const int ktmax = 31 - ja;

    const int SE = 3 * Ec;
    const size_t hbase = (size_t)b * Sc * SE + (size_t)h * (3 * HDc);

    // Q fragments (register-resident)
    half8v qfa[2], qfb[2];
    #pragma unroll
    for (int kk = 0; kk < 2; ++kk) {
        qfa[kk] = *(const half8v*)(qkv + hbase + (size_t)(qa0 + c15) * SE + kk * 32 + q * 8);
        qfb[kk] = *(const half8v*)(qkv + hbase + (size_t)(qb0 + c15) * SE + kk * 32 + q * 8);
    }

    f32x4 O[2][4];
    #pragma unroll
    for (int i = 0; i < 2; ++i)
        #pragma unroll
        for (int n = 0; n < 4; ++n)
            O[i][n] = (f32x4){0.f, 0.f, 0.f, 0.f};
    float mi[2] = {-3e38f, -3e38f}, li[2] = {0.f, 0.f};

    const int krow = t >> 2, kjj = t & 3;          // K staging
    const int vkey = t & 31, vd0 = (t >> 5) << 3;  // V staging
    half8v vreg[2];

    // --- staging helpers ---
    auto stageK = [&](int kt, int bf) {
        #pragma unroll
        for (int p = 0; p < 2; ++p)
            gld_lds16(qkv + hbase + (size_t)(kt * 64 + krow) * SE + HDc + p * 32 + kjj * 8,
                      &Ks[bf][p][krow * 32 + kjj * 8]);
    };
    auto loadV = [&](int kt) {
        #pragma unroll
        for (int p = 0; p < 2; ++p)
            vreg[p] = *(const half8v*)(qkv + hbase +
                        (size_t)(kt * 64 + p * 32 + vkey) * SE + 2 * HDc + vd0);
    };
    auto scatV = [&](int bf) {
        #pragma unroll
        for (int p = 0; p < 2; ++p)
            #pragma unroll
            for (int u = 0; u < 8; ++u)
                Vt[bf][p][(vd0 + u) * 32 + vkey] = vreg[p][u];
    };

    stageK(0, 0); loadV(0); scatV(0);

    for (int kt = 0; kt <= ktmax; ++kt) {
        const int bf = kt & 1;
        __syncthreads();
        if (kt < ktmax) { stageK(kt + 1, bf ^ 1); loadV(kt + 1); }
        const int k0 = kt * 64;

        half8v kf[4][2];
        #pragma unroll
        for (int j = 0; j < 4; ++j)
            #pragma unroll
            for (int kk = 0; kk < 2; ++kk)
                kf[j][kk] = *(const half8v*)&Ks[bf][kk][(j * 16 + c15) * 32 + q * 8];

        #pragma unroll
        for (int i = 0; i < 2; ++i) {
            if (i == 0 && kt > ja) continue;   // tile_a fully masked (uniform)
            const half8v* qf = i ? qfb : qfa;
            const int qrow = (i ? qb0 : qa0) + c15;   // this lane's query

            // S^T tile: rows=keys (q*4+r per j), col=query (c15)
            f32x4 st[4];
            #pragma unroll
            for (int j = 0; j < 4; ++j) {
                f32x4 z = (f32x4){0.f, 0.f, 0.f, 0.f};
                z = __builtin_amdgcn_mfma_f32_16x16x32_f16(kf[j][0], qf[0], z, 0, 0, 0);
                st[j] = __builtin_amdgcn_mfma_f32_16x16x32_f16(kf[j][1], qf[1], st[j] = z, 0, 0, 0);
            }

            float sv[16];
            float mx = mi[i];
            #pragma unroll
            for (int j = 0; j < 4; ++j)
                #pragma unroll
                for (int r = 0; r < 4; ++r) {
                    int key = k0 + j * 16 + q * 4 + r;
                    float v = st[j][r] * 0.125f;
                    v = (key <= qrow) ? v : -3e38f;
                    sv[j * 4 + r] = v;
                    mx = fmaxf(mx, v);
                }
            mx = fmaxf(mx, __shfl_xor(mx, 16, 64));
            mx = fmaxf(mx, __shfl_xor(mx, 32, 64));
            float al = __expf(mi[i] - mx);
            mi[i] = mx;
            float ps = 0.f;
            #pragma unroll
            for (int j = 0; j < 4; ++j)
                #pragma unroll
                for (int r = 0; r < 4; ++r) {
                    float p = __expf(sv[j * 4 + r] - mx);
                    ps += p;
                    Ps[wv][i][c15 * 72 + j * 16 + q * 4 + r] = (h16)p;
                }
            ps += __shfl_xor(ps, 16, 64);
            ps += __shfl_xor(ps, 32, 64);
            li[i] = li[i] * al + ps;

            // broadcast alpha to C-layout rows, rescale O
            float alr[4];
            #pragma unroll
            for (int r = 0; r < 4; ++r) alr[r] = __shfl(al, q * 4 + r, 64);
            #pragma unroll
            for (int n = 0; n < 4; ++n)
                #pragma unroll
                for (int r = 0; r < 4; ++r) O[i][n][r] *= alr[r];

            // PV: A = P[query][key] (pad-72 rows), B = V^T[d][key]
            half8v pa0 = *(const half8v*)&Ps[wv][i][c15 * 72 + q * 8];
            half8v pa1 = *(const half8v*)&Ps[wv][i][c15 * 72 + 32 + q * 8];
            #pragma unroll
            for (int n = 0; n < 4; ++n) {
                half8v vf0 = *(const half8v*)&Vt[bf][0][(n * 16 + c15) * 32 + q * 8];
                half8v vf1 = *(const half8v*)&Vt[bf][1][(n * 16 + c15) * 32 + q * 8];
                O[i][n] = __builtin_amdgcn_mfma_f32_16x16x32_f16(pa0, vf0, O[i][n], 0, 0, 0);
                O[i][n] = __builtin_amdgcn_mfma_f32_16x16x32_f16(pa1, vf1, O[i][n], 0, 0, 0);
            }
        }
        if (kt < ktmax) scatV(bf ^ 1);
    }

    #pragma unroll
    for (int i = 0; i < 2; ++i) {
        int qb0i = i ? qb0 : qa0;
        float lr[4];
        #pragma unroll
        for (int r = 0; r < 4; ++r) lr[r] = __shfl(li[i], q * 4 + r, 64);
        #pragma unroll
        for (int r = 0; r < 4; ++r) {
            int row = qb0i + q * 4 + r;
            float rl = 1.0f / lr[r];
            #pragma unroll
            for (int n = 0; n < 4; ++n)
                attn[((size_t)(b * Sc + row)) * Ec + h * HDc + n * 16 + c15] =
                    (h16)(O[i][n][r] * rl);
        }
    }
}

// ---------------------------------------------------------------------------
extern "C" void kernel_launch(void* const* d_in, const int* in_sizes, int n_in,
                              void* d_out, int out_size, void* d_ws, size_t ws_size,
                              hipStream_t stream) {
    const float* x     = (const float*)d_in[0];
    const float* ln1_g = (const float*)d_in[1];
    const float* ln1_b = (const float*)d_in[2];
    const float* ln2_g = (const float*)d_in[3];
    const float* ln2_b = (const float*)d_in[4];
    const float* w_qkv = (const float*)d_in[5];
    const float* b_qkv = (const float*)d_in[6];
    const float* w_ao  = (const float*)d_in[7];
    const float* b_ao  = (const float*)d_in[8];
    const float* w_fc  = (const float*)d_in[9];
    const float* b_fc  = (const float*)d_in[10];
    const float* w_po  = (const float*)d_in[11];
    const float* b_po  = (const float*)d_in[12];
    float* out = (float*)d_out;

    // workspace (80 MB total):
    char* w = (char*)d_ws;
    h16* wqkv = (h16*)(w);             // 6 MB
    h16* wao  = (h16*)(w + 6291456);   // 2 MB
    h16* wfc  = (h16*)(w + 8388608);   // 8 MB
    h16* wpo  = (h16*)(w + 16777216);  // 8 MB
    h16* hb   = (h16*)(w + 25165824);  // 8 MB  (fp16 LN out, reused)
    h16* qkv  = (h16*)(w + 33554432);  // 24 MB
    h16* attn = (h16*)(w + 58720256);  // 8 MB
    float* x1 = (float*)(w + 67108864);// 16 MB
    h16* ff   = qkv;                   // 32 MB alias over qkv+attn (dead)

    dim3 blk(256);

    // weight converts fp32 -> fp16
    cvt_kernel<<<dim3(3 * Ec * Ec / 1024), blk, 0, stream>>>(w_qkv, wqkv, 3 * Ec * Ec);
    cvt_kernel<<<dim3(Ec * Ec / 1024), blk, 0, stream>>>(w_ao, wao, Ec * Ec);
    cvt_kernel<<<dim3(DFFc * Ec / 1024), blk, 0, stream>>>(w_fc, wfc, DFFc * Ec);
    cvt_kernel<<<dim3(Ec * DFFc / 1024), blk, 0, stream>>>(w_po, wpo, Ec * DFFc);

    // 1. hb = LN1(x)
    ln_kernel<<<dim3(ROWS), blk, 0, stream>>>(x, ln1_g, ln1_b, hb);
    // 2. qkv = hb @ w_qkv^T + b_qkv   (fp16 out)
    gemm_mfma<0, h16><<<dim3(3 * Ec / 128, ROWS / 128), blk, 0, stream>>>(
        hb, wqkv, b_qkv, nullptr, qkv, ROWS, 3 * Ec, Ec);
    // 3. attn = causal_flash_attention(qkv)   (fp16 out)
    attn_mfma<<<dim3(16, Bc * Hc), blk, 0, stream>>>(qkv, attn);
    // 4. x1 = x + attn @ w_ao^T + b_ao  (fp32)  [skinny-N deep-K kernel]
    gemm_k64<1, float><<<dim3(Ec / 128, ROWS / 64), blk, 0, stream>>>(
        attn, wao, b_ao, x, x1, ROWS, Ec, Ec);
    // 5. hb = LN2(x1)
    ln_kernel<<<dim3(ROWS), blk, 0, stream>>>(x1, ln2_g, ln2_b, hb);
    // 6. ff = gelu(hb @ w_fc^T + b_fc)  (fp16)
    gemm_mfma<2, h16><<<dim3(DFFc / 128, ROWS / 128), blk, 0, stream>>>(
        hb, wfc, b_fc, nullptr, ff, ROWS, DFFc, Ec);
    // 7. out = x1 + ff @ w_po^T + b_po  (fp32)  [skinny-N deep-K kernel]
    gemm_k64<1, float><<<dim3(Ec / 128, ROWS / 64), blk, 0, stream>>>(
        ff, wpo, b_po, x1, out, ROWS, Ec, DFFc);
}

// Round 7
// 364.732 us; speedup vs baseline: 9.5443x; 1.0416x over previous
//
#include <hip/hip_runtime.h>
#include <cstddef>
#include <cstdint>

#define Bc 2
#define Sc 2048
#define Ec 1024
#define Hc 16
#define HDc 64
#define DFFc 4096
#define ROWS (Bc * Sc)  // 4096

typedef _Float16 half8v __attribute__((ext_vector_type(8)));  // 8 fp16 (4 VGPR)
typedef _Float16 half4v __attribute__((ext_vector_type(4)));
typedef float f32x4 __attribute__((ext_vector_type(4)));      // MFMA C/D frag
typedef _Float16 h16;

// async global->LDS, 16B per lane. LDS dest must be wave-uniform base + lane*16.
__device__ inline void gld_lds16(const void* g, void* l) {
    __builtin_amdgcn_global_load_lds(
        (const __attribute__((address_space(1))) void*)g,
        (__attribute__((address_space(3))) void*)l, 16, 0, 0);
}

// gelu_new via sigmoid identity: 0.5x(1+tanh(z)) == x*sigmoid(2z).
__device__ inline float gelu_new(float x) {
    float u = 1.5957691216057308f * fmaf(0.044715f * x * x, x, x);
    return x / (1.0f + __expf(-u));
}

// ---------------------------------------------------------------------------
// fp32 -> fp16 convert (weights), n % 1024 == 0
// ---------------------------------------------------------------------------
__global__ __launch_bounds__(256) void cvt_kernel(const float* __restrict__ in,
                                                  h16* __restrict__ out, int n) {
    int i = (blockIdx.x * 256 + threadIdx.x) * 4;
    float4 v = *(const float4*)(in + i);
    half4v o;
    o.x = (h16)v.x; o.y = (h16)v.y; o.z = (h16)v.z; o.w = (h16)v.w;
    *(half4v*)(out + i) = o;
}

// ---------------------------------------------------------------------------
// LayerNorm: fp32 in, fp16 out. One block per row of E=1024.
// ---------------------------------------------------------------------------
__device__ inline float block_sum256(float v, float* sb) {
    #pragma unroll
    for (int o = 32; o > 0; o >>= 1) v += __shfl_down(v, o, 64);
    int lane = threadIdx.x & 63, w = threadIdx.x >> 6;
    if (lane == 0) sb[w] = v;
    __syncthreads();
    float r = sb[0] + sb[1] + sb[2] + sb[3];
    __syncthreads();
    return r;
}

__global__ __launch_bounds__(256) void ln_kernel(const float* __restrict__ x,
                                                 const float* __restrict__ g,
                                                 const float* __restrict__ b,
                                                 h16* __restrict__ out) {
    __shared__ float sb[4];
    int row = blockIdx.x;
    int t = threadIdx.x;
    const float* xr = x + (size_t)row * Ec;
    float4 v = ((const float4*)xr)[t];
    float s = v.x + v.y + v.z + v.w;
    float mu = block_sum256(s, sb) * (1.0f / Ec);
    float dx = v.x - mu, dy = v.y - mu, dz = v.z - mu, dw = v.w - mu;
    float ss = dx * dx + dy * dy + dz * dz + dw * dw;
    float var = block_sum256(ss, sb) * (1.0f / Ec);
    float inv = rsqrtf(var + 1e-5f);
    float4 gv = ((const float4*)g)[t];
    float4 bv = ((const float4*)b)[t];
    half4v o;
    o.x = (h16)(dx * inv * gv.x + bv.x);
    o.y = (h16)(dy * inv * gv.y + bv.y);
    o.z = (h16)(dz * inv * gv.z + bv.z);
    o.w = (h16)(dw * inv * gv.w + bv.w);
    ((half4v*)(out + (size_t)row * Ec))[t] = o;
}

// ---------------------------------------------------------------------------
// fp16 MFMA GEMM (big tile): BM=BN=128, BK=64 as 2 x BK32 sub-buffers.
// 256 threads = 4 waves in 2x2; 32 MFMA/wave/barrier.
// ---------------------------------------------------------------------------
template <int EPI, typename OutT>
__global__ __launch_bounds__(256) void gemm_mfma(
    const h16* __restrict__ A, const h16* __restrict__ W,
    const float* __restrict__ bias, const float* __restrict__ R,
    OutT* __restrict__ C, int M, int N, int K)
{
    __shared__ h16 As[2][128 * 32];   // 16 KB
    __shared__ h16 Ws[2][128 * 32];   // 16 KB

    const int t = threadIdx.x;
    const int lane = t & 63, wv = t >> 6;
    const int wm = wv >> 1, wn = wv & 1;
    const int c15 = lane & 15, q = lane >> 4;
    const int row0 = blockIdx.y * 128, col0 = blockIdx.x * 128;
    const int arow = t >> 2, acol = (t & 3) << 3;  // staging row / col8

    f32x4 acc[4][4];
    #pragma unroll
    for (int i = 0; i < 4; ++i)
        #pragma unroll
        for (int j = 0; j < 4; ++j)
            acc[i][j] = (f32x4){0.f, 0.f, 0.f, 0.f};

    for (int k0 = 0; k0 < K; k0 += 64) {
        __syncthreads();
        #pragma unroll
        for (int kk = 0; kk < 2; ++kk)
            #pragma unroll
            for (int p = 0; p < 2; ++p) {
                int r = p * 64 + arow;
                gld_lds16(A + (size_t)(row0 + r) * K + k0 + kk * 32 + acol,
                          &As[kk][r * 32 + acol]);
                gld_lds16(W + (size_t)(col0 + r) * K + k0 + kk * 32 + acol,
                          &Ws[kk][r * 32 + acol]);
            }
        __syncthreads();

        #pragma unroll
        for (int kk = 0; kk < 2; ++kk) {
            half8v af[4], bf[4];
            #pragma unroll
            for (int i = 0; i < 4; ++i)
                af[i] = *(const half8v*)&As[kk][(wm * 64 + i * 16 + c15) * 32 + q * 8];
            #pragma unroll
            for (int j = 0; j < 4; ++j)
                bf[j] = *(const half8v*)&Ws[kk][(wn * 64 + j * 16 + c15) * 32 + q * 8];
            #pragma unroll
            for (int i = 0; i < 4; ++i)
                #pragma unroll
                for (int j = 0; j < 4; ++j)
                    acc[i][j] = __builtin_amdgcn_mfma_f32_16x16x32_f16(af[i], bf[j], acc[i][j], 0, 0, 0);
        }
    }

    #pragma unroll
    for (int i = 0; i < 4; ++i) {
        #pragma unroll
        for (int j = 0; j < 4; ++j) {
            int col = col0 + wn * 64 + j * 16 + c15;
            float bv = bias[col];
            #pragma unroll
            for (int r = 0; r < 4; ++r) {
                int row = row0 + wm * 64 + i * 16 + q * 4 + r;
                size_t off = (size_t)row * N + col;
                float v = acc[i][j][r] + bv;
                if (EPI == 1) v += R[off];
                if (EPI == 2) v = gelu_new(v);
                if (sizeof(OutT) == 2) ((h16*)C)[off] = (h16)v;
                else ((float*)C)[off] = v;
            }
        }
    }
}

// ---------------------------------------------------------------------------
// fp16 MFMA GEMM (skinny-N, deep-K): BM=64, BN=128, BK=64 as 2 x BK32 buffers.
// ---------------------------------------------------------------------------
template <int EPI, typename OutT>
__global__ __launch_bounds__(256) void gemm_k64(
    const h16* __restrict__ A, const h16* __restrict__ W,
    const float* __restrict__ bias, const float* __restrict__ R,
    OutT* __restrict__ C, int M, int N, int K)
{
    __shared__ h16 As[2][64 * 32];    // 8 KB
    __shared__ h16 Ws[2][128 * 32];   // 16 KB

    const int t = threadIdx.x;
    const int lane = t & 63, wv = t >> 6;
    const int wm = wv >> 1, wn = wv & 1;
    const int c15 = lane & 15, q = lane >> 4;
    const int row0 = blockIdx.y * 64, col0 = blockIdx.x * 128;
    const int arow = t >> 2, acol = (t & 3) << 3;

    f32x4 acc[2][4];
    #pragma unroll
    for (int i = 0; i < 2; ++i)
        #pragma unroll
        for (int j = 0; j < 4; ++j)
            acc[i][j] = (f32x4){0.f, 0.f, 0.f, 0.f};

    for (int k0 = 0; k0 < K; k0 += 64) {
        __syncthreads();
        #pragma unroll
        for (int kk = 0; kk < 2; ++kk) {
            gld_lds16(A + (size_t)(row0 + arow) * K + k0 + kk * 32 + acol,
                      &As[kk][arow * 32 + acol]);
            #pragma unroll
            for (int p = 0; p < 2; ++p) {
                int r = p * 64 + arow;
                gld_lds16(W + (size_t)(col0 + r) * K + k0 + kk * 32 + acol,
                          &Ws[kk][r * 32 + acol]);
            }
        }
        __syncthreads();

        #pragma unroll
        for (int kk = 0; kk < 2; ++kk) {
            half8v af[2], bf[4];
            #pragma unroll
            for (int i = 0; i < 2; ++i)
                af[i] = *(const half8v*)&As[kk][(wm * 32 + i * 16 + c15) * 32 + q * 8];
            #pragma unroll
            for (int j = 0; j < 4; ++j)
                bf[j] = *(const half8v*)&Ws[kk][(wn * 64 + j * 16 + c15) * 32 + q * 8];
            #pragma unroll
            for (int i = 0; i < 2; ++i)
                #pragma unroll
                for (int j = 0; j < 4; ++j)
                    acc[i][j] = __builtin_amdgcn_mfma_f32_16x16x32_f16(af[i], bf[j], acc[i][j], 0, 0, 0);
        }
    }

    #pragma unroll
    for (int i = 0; i < 2; ++i) {
        #pragma unroll
        for (int j = 0; j < 4; ++j) {
            int col = col0 + wn * 64 + j * 16 + c15;
            float bv = bias[col];
            #pragma unroll
            for (int r = 0; r < 4; ++r) {
                int row = row0 + wm * 32 + i * 16 + q * 4 + r;
                size_t off = (size_t)row * N + col;
                float v = acc[i][j][r] + bv;
                if (EPI == 1) v += R[off];
                if (EPI == 2) v = gelu_new(v);
                if (sizeof(OutT) == 2) ((h16*)C)[off] = (h16)v;
                else ((float*)C)[off] = v;
            }
        }
    }
}

// ---------------------------------------------------------------------------
// Causal flash attention v3, fp16 MFMA, O^T formulation.
// Grid (32 bh, 32 q-tiles), ja = 31 - blockIdx.y (long blocks first).
// Block = 4 waves; wave owns 16 query rows (query = c15 lane).
// S^T = K*Q^T -> col=query=c15; O^T = V^T*P^T -> col=query=c15: all softmax
// state (m,l,alpha) is lane-local, zero shuffle broadcasts.
// K double-buffered via global_load_lds; V single-buffer reg-prefetch+scatter.
// LDS 33 KB -> 4 blocks/CU.
// ---------------------------------------------------------------------------
__global__ __launch_bounds__(256, 4) void attn_mfma(const h16* __restrict__ qkv,
                                                    h16* __restrict__ attn) {
    __shared__ h16 Ks[2][2][64 * 32];   // [buf][d-half][key*32+d]   16 KB
    __shared__ h16 Vt[2][64 * 32];      // [key-half][d*32+key]       8 KB
    __shared__ h16 Ps[4][16 * 72];      // [wave][query*72+key]       9 KB

    const int t = threadIdx.x;
    const int lane = t & 63, wv = t >> 6;
    const int c15 = lane & 15, q = lane >> 4;
    const int bh = blockIdx.x, b = bh >> 4, h = bh & 15;
    const int ja = 31 - blockIdx.y;       // long blocks dispatch first
    const int qbase = ja * 64 + wv * 16;  // wave's 16 query rows
    const int SE = 3 * Ec;
    const size_t hbase = (size_t)b * Sc * SE + (size_t)h * (3 * HDc);

    // Q fragment, pre-scaled by 1/sqrt(64) = 0.125 (exact in fp16)
    half8v qf[2];
    #pragma unroll
    for (int kk = 0; kk < 2; ++kk) {
        qf[kk] = *(const half8v*)(qkv + hbase + (size_t)(qbase + c15) * SE + kk * 32 + q * 8);
        qf[kk] *= (h16)0.125f;
    }

    f32x4 O[4];   // O^T: [d-tile], col=query(c15), row=d-local(q*4+r)
    #pragma unroll
    for (int n = 0; n < 4; ++n) O[n] = (f32x4){0.f, 0.f, 0.f, 0.f};
    float mi = -3e38f, li = 0.f;

    const int krow = t >> 2, kcol = (t & 3) << 3;   // K staging (gld_lds16)
    const int vkey = t & 31, vd0 = (t >> 5) << 3;   // V staging
    half8v vreg[2];

    auto stageK = [&](int kt, int bf) {
        #pragma unroll
        for (int p = 0; p < 2; ++p)
            gld_lds16(qkv + hbase + (size_t)(kt * 64 + krow) * SE + HDc + p * 32 + kcol,
                      &Ks[bf][p][krow * 32 + kcol]);
    };
    auto loadV = [&](int kt) {
        #pragma unroll
        for (int p = 0; p < 2; ++p)
            vreg[p] = *(const half8v*)(qkv + hbase +
                        (size_t)(kt * 64 + p * 32 + vkey) * SE + 2 * HDc + vd0);
    };
    auto scatV = [&]() {
        #pragma unroll
        for (int p = 0; p < 2; ++p)
            #pragma unroll
            for (int u = 0; u < 8; ++u)
                Vt[p][(vd0 + u) * 32 + vkey] = vreg[p][u];
    };

    stageK(0, 0);
    loadV(0);
    scatV();
    __syncthreads();

    for (int kt = 0; kt <= ja; ++kt) {
        const int bf = kt & 1;
        if (kt < ja) { stageK(kt + 1, bf ^ 1); loadV(kt + 1); }

        // S^T = K*Q^T : st[j] rows=key-local(q*4+r), col=query(c15)
        f32x4 st[4];
        #pragma unroll
        for (int j = 0; j < 4; ++j) {
            half8v kf0 = *(const half8v*)&Ks[bf][0][(j * 16 + c15) * 32 + q * 8];
            half8v kf1 = *(const half8v*)&Ks[bf][1][(j * 16 + c15) * 32 + q * 8];
            f32x4 z = (f32x4){0.f, 0.f, 0.f, 0.f};
            z = __builtin_amdgcn_mfma_f32_16x16x32_f16(kf0, qf[0], z, 0, 0, 0);
            st[j] = __builtin_amdgcn_mfma_f32_16x16x32_f16(kf1, qf[1], z, 0, 0, 0);
        }

        // causal mask: only the diagonal tile needs it (wave-uniform branch)
        if (kt == ja) {
            const int rowloc = wv * 16 + c15;
            #pragma unroll
            for (int j = 0; j < 4; ++j)
                #pragma unroll
                for (int r = 0; r < 4; ++r)
                    if (j * 16 + q * 4 + r > rowloc) st[j][r] = -3e38f;
        }

        // online softmax; query owned by c15, its 64 keys spread over 4 q-groups
        float mx = mi;
        #pragma unroll
        for (int j = 0; j < 4; ++j)
            #pragma unroll
            for (int r = 0; r < 4; ++r) mx = fmaxf(mx, st[j][r]);
        mx = fmaxf(mx, __shfl_xor(mx, 16, 64));
        mx = fmaxf(mx, __shfl_xor(mx, 32, 64));
        float al = __expf(mi - mx);
        mi = mx;
        float ps = 0.f;
        #pragma unroll
        for (int j = 0; j < 4; ++j) {
            half4v pk;
            #pragma unroll
            for (int r = 0; r < 4; ++r) {
                float p = __expf(st[j][r] - mx);
                ps += p;
                pk[r] = (h16)p;
            }
            *(half4v*)&Ps[wv][c15 * 72 + j * 16 + q * 4] = pk;
        }
        ps += __shfl_xor(ps, 16, 64);
        ps += __shfl_xor(ps, 32, 64);
        li = li * al + ps;

        // O^T += V^T * P^T ; alpha-rescale is lane-local (col=query=c15)
        half8v pb0 = *(const half8v*)&Ps[wv][c15 * 72 + q * 8];
        half8v pb1 = *(const half8v*)&Ps[wv][c15 * 72 + 32 + q * 8];
        #pragma unroll
        for (int n = 0; n < 4; ++n) {
            #pragma unroll
            for (int r = 0; r < 4; ++r) O[n][r] *= al;
            half8v va0 = *(const half8v*)&Vt[0][(n * 16 + c15) * 32 + q * 8];
            half8v va1 = *(const half8v*)&Vt[1][(n * 16 + c15) * 32 + q * 8];
            O[n] = __builtin_amdgcn_mfma_f32_16x16x32_f16(va0, pb0, O[n], 0, 0, 0);
            O[n] = __builtin_amdgcn_mfma_f32_16x16x32_f16(va1, pb1, O[n], 0, 0, 0);
        }

        if (kt < ja) {
            __syncthreads();   // all waves done reading Vt (and Ks[bf])
            scatV();           // write V(kt+1) into single Vt buffer
            __syncthreads();   // Vt + async Ks[bf^1] (vmcnt drain) ready
        }
    }

    // epilogue: query = qbase+c15, d = n*16 + q*4 + r (4 contiguous -> 8B store)
    float rl = 1.0f / li;
    #pragma unroll
    for (int n = 0; n < 4; ++n) {
        half4v o4;
        #pragma unroll
        for (int r = 0; r < 4; ++r) o4[r] = (h16)(O[n][r] * rl);
        *(half4v*)(attn + ((size_t)(b * Sc + qbase + c15)) * Ec + h * HDc + n * 16 + q * 4) = o4;
    }
}

// ---------------------------------------------------------------------------
extern "C" void kernel_launch(void* const* d_in, const int* in_sizes, int n_in,
                              void* d_out, int out_size, void* d_ws, size_t ws_size,
                              hipStream_t stream) {
    const float* x     = (const float*)d_in[0];
    const float* ln1_g = (const float*)d_in[1];
    const float* ln1_b = (const float*)d_in[2];
    const float* ln2_g = (const float*)d_in[3];
    const float* ln2_b = (const float*)d_in[4];
    const float* w_qkv = (const float*)d_in[5];
    const float* b_qkv = (const float*)d_in[6];
    const float* w_ao  = (const float*)d_in[7];
    const float* b_ao  = (const float*)d_in[8];
    const float* w_fc  = (const float*)d_in[9];
    const float* b_fc  = (const float*)d_in[10];
    const float* w_po  = (const float*)d_in[11];
    const float* b_po  = (const float*)d_in[12];
    float* out = (float*)d_out;

    // workspace (80 MB total):
    char* w = (char*)d_ws;
    h16* wqkv = (h16*)(w);             // 6 MB
    h16* wao  = (h16*)(w + 6291456);   // 2 MB
    h16* wfc  = (h16*)(w + 8388608);   // 8 MB
    h16* wpo  = (h16*)(w + 16777216);  // 8 MB
    h16* hb   = (h16*)(w + 25165824);  // 8 MB  (fp16 LN out, reused)
    h16* qkv  = (h16*)(w + 33554432);  // 24 MB
    h16* attn = (h16*)(w + 58720256);  // 8 MB
    float* x1 = (float*)(w + 67108864);// 16 MB
    h16* ff   = qkv;                   // 32 MB alias over qkv+attn (dead)

    dim3 blk(256);

    // weight converts fp32 -> fp16
    cvt_kernel<<<dim3(3 * Ec * Ec / 1024), blk, 0, stream>>>(w_qkv, wqkv, 3 * Ec * Ec);
    cvt_kernel<<<dim3(Ec * Ec / 1024), blk, 0, stream>>>(w_ao, wao, Ec * Ec);
    cvt_kernel<<<dim3(DFFc * Ec / 1024), blk, 0, stream>>>(w_fc, wfc, DFFc * Ec);
    cvt_kernel<<<dim3(Ec * DFFc / 1024), blk, 0, stream>>>(w_po, wpo, Ec * DFFc);

    // 1. hb = LN1(x)
    ln_kernel<<<dim3(ROWS), blk, 0, stream>>>(x, ln1_g, ln1_b, hb);
    // 2. qkv = hb @ w_qkv^T + b_qkv   (fp16 out)
    gemm_mfma<0, h16><<<dim3(3 * Ec / 128, ROWS / 128), blk, 0, stream>>>(
        hb, wqkv, b_qkv, nullptr, qkv, ROWS, 3 * Ec, Ec);
    // 3. attn = causal_flash_attention(qkv)   (fp16 out)
    attn_mfma<<<dim3(Bc * Hc, 32), blk, 0, stream>>>(qkv, attn);
    // 4. x1 = x + attn @ w_ao^T + b_ao  (fp32)
    gemm_k64<1, float><<<dim3(Ec / 128, ROWS / 64), blk, 0, stream>>>(
        attn, wao, b_ao, x, x1, ROWS, Ec, Ec);
    // 5. hb = LN2(x1)
    ln_kernel<<<dim3(ROWS), blk, 0, stream>>>(x1, ln2_g, ln2_b, hb);
    // 6. ff = gelu(hb @ w_fc^T + b_fc)  (fp16)
    gemm_mfma<2, h16><<<dim3(DFFc / 128, ROWS / 128), blk, 0, stream>>>(
        hb, wfc, b_fc, nullptr, ff, ROWS, DFFc, Ec);
    // 7. out = x1 + ff @ w_po^T + b_po  (fp32)
    gemm_k64<1, float><<<dim3(Ec / 128, ROWS / 64), blk, 0, stream>>>(
        ff, wpo, b_po, x1, out, ROWS, Ec, DFFc);
}

// Round 8
// 352.326 us; speedup vs baseline: 9.8803x; 1.0352x over previous
//
#include <hip/hip_runtime.h>
#include <cstddef>
#include <cstdint>

#define Bc 2
#define Sc 2048
#define Ec 1024
#define Hc 16
#define HDc 64
#define DFFc 4096
#define ROWS (Bc * Sc)  // 4096

typedef _Float16 half8v __attribute__((ext_vector_type(8)));  // 8 fp16 (4 VGPR)
typedef _Float16 half4v __attribute__((ext_vector_type(4)));
typedef float f32x4 __attribute__((ext_vector_type(4)));      // MFMA C/D frag
typedef _Float16 h16;

// async global->LDS, 16B per lane. LDS dest must be wave-uniform base + lane*16.
__device__ inline void gld_lds16(const void* g, void* l) {
    __builtin_amdgcn_global_load_lds(
        (const __attribute__((address_space(1))) void*)g,
        (__attribute__((address_space(3))) void*)l, 16, 0, 0);
}

// gelu_new via sigmoid identity: 0.5x(1+tanh(z)) == x*sigmoid(2z).
__device__ inline float gelu_new(float x) {
    float u = 1.5957691216057308f * fmaf(0.044715f * x * x, x, x);
    return x / (1.0f + __expf(-u));
}

// ---------------------------------------------------------------------------
// fp32 -> fp16 convert (weights), n % 1024 == 0
// ---------------------------------------------------------------------------
__global__ __launch_bounds__(256) void cvt_kernel(const float* __restrict__ in,
                                                  h16* __restrict__ out, int n) {
    int i = (blockIdx.x * 256 + threadIdx.x) * 4;
    float4 v = *(const float4*)(in + i);
    half4v o;
    o.x = (h16)v.x; o.y = (h16)v.y; o.z = (h16)v.z; o.w = (h16)v.w;
    *(half4v*)(out + i) = o;
}

// ---------------------------------------------------------------------------
// LayerNorm: fp32 in, fp16 out. One block per row of E=1024.
// ---------------------------------------------------------------------------
__device__ inline float block_sum256(float v, float* sb) {
    #pragma unroll
    for (int o = 32; o > 0; o >>= 1) v += __shfl_down(v, o, 64);
    int lane = threadIdx.x & 63, w = threadIdx.x >> 6;
    if (lane == 0) sb[w] = v;
    __syncthreads();
    float r = sb[0] + sb[1] + sb[2] + sb[3];
    __syncthreads();
    return r;
}

__global__ __launch_bounds__(256) void ln_kernel(const float* __restrict__ x,
                                                 const float* __restrict__ g,
                                                 const float* __restrict__ b,
                                                 h16* __restrict__ out) {
    __shared__ float sb[4];
    int row = blockIdx.x;
    int t = threadIdx.x;
    const float* xr = x + (size_t)row * Ec;
    float4 v = ((const float4*)xr)[t];
    float s = v.x + v.y + v.z + v.w;
    float mu = block_sum256(s, sb) * (1.0f / Ec);
    float dx = v.x - mu, dy = v.y - mu, dz = v.z - mu, dw = v.w - mu;
    float ss = dx * dx + dy * dy + dz * dz + dw * dw;
    float var = block_sum256(ss, sb) * (1.0f / Ec);
    float inv = rsqrtf(var + 1e-5f);
    float4 gv = ((const float4*)g)[t];
    float4 bv = ((const float4*)b)[t];
    half4v o;
    o.x = (h16)(dx * inv * gv.x + bv.x);
    o.y = (h16)(dy * inv * gv.y + bv.y);
    o.z = (h16)(dz * inv * gv.z + bv.z);
    o.w = (h16)(dw * inv * gv.w + bv.w);
    ((half4v*)(out + (size_t)row * Ec))[t] = o;
}

// ---------------------------------------------------------------------------
// fp16 MFMA GEMM (big tile): BM=BN=128, BK=64 as 2 x BK32 sub-buffers.
// 256 threads = 4 waves in 2x2; 32 MFMA/wave/barrier.
// ---------------------------------------------------------------------------
template <int EPI, typename OutT>
__global__ __launch_bounds__(256) void gemm_mfma(
    const h16* __restrict__ A, const h16* __restrict__ W,
    const float* __restrict__ bias, const float* __restrict__ R,
    OutT* __restrict__ C, int M, int N, int K)
{
    __shared__ h16 As[2][128 * 32];   // 16 KB
    __shared__ h16 Ws[2][128 * 32];   // 16 KB

    const int t = threadIdx.x;
    const int lane = t & 63, wv = t >> 6;
    const int wm = wv >> 1, wn = wv & 1;
    const int c15 = lane & 15, q = lane >> 4;
    const int row0 = blockIdx.y * 128, col0 = blockIdx.x * 128;
    const int arow = t >> 2, acol = (t & 3) << 3;  // staging row / col8

    f32x4 acc[4][4];
    #pragma unroll
    for (int i = 0; i < 4; ++i)
        #pragma unroll
        for (int j = 0; j < 4; ++j)
            acc[i][j] = (f32x4){0.f, 0.f, 0.f, 0.f};

    for (int k0 = 0; k0 < K; k0 += 64) {
        __syncthreads();
        #pragma unroll
        for (int kk = 0; kk < 2; ++kk)
            #pragma unroll
            for (int p = 0; p < 2; ++p) {
                int r = p * 64 + arow;
                gld_lds16(A + (size_t)(row0 + r) * K + k0 + kk * 32 + acol,
                          &As[kk][r * 32 + acol]);
                gld_lds16(W + (size_t)(col0 + r) * K + k0 + kk * 32 + acol,
                          &Ws[kk][r * 32 + acol]);
            }
        __syncthreads();

        #pragma unroll
        for (int kk = 0; kk < 2; ++kk) {
            half8v af[4], bf[4];
            #pragma unroll
            for (int i = 0; i < 4; ++i)
                af[i] = *(const half8v*)&As[kk][(wm * 64 + i * 16 + c15) * 32 + q * 8];
            #pragma unroll
            for (int j = 0; j < 4; ++j)
                bf[j] = *(const half8v*)&Ws[kk][(wn * 64 + j * 16 + c15) * 32 + q * 8];
            #pragma unroll
            for (int i = 0; i < 4; ++i)
                #pragma unroll
                for (int j = 0; j < 4; ++j)
                    acc[i][j] = __builtin_amdgcn_mfma_f32_16x16x32_f16(af[i], bf[j], acc[i][j], 0, 0, 0);
        }
    }

    #pragma unroll
    for (int i = 0; i < 4; ++i) {
        #pragma unroll
        for (int j = 0; j < 4; ++j) {
            int col = col0 + wn * 64 + j * 16 + c15;
            float bv = bias[col];
            #pragma unroll
            for (int r = 0; r < 4; ++r) {
                int row = row0 + wm * 64 + i * 16 + q * 4 + r;
                size_t off = (size_t)row * N + col;
                float v = acc[i][j][r] + bv;
                if (EPI == 1) v += R[off];
                if (EPI == 2) v = gelu_new(v);
                if (sizeof(OutT) == 2) ((h16*)C)[off] = (h16)v;
                else ((float*)C)[off] = v;
            }
        }
    }
}

// ---------------------------------------------------------------------------
// fp16 MFMA GEMM (skinny-N, deep-K): BM=64, BN=128, BK=128 as 4 x BK32
// sub-buffers (keeps 64B-row-stride conflict-free layout + lane*16 LDS dest).
// 256 threads = 4 waves in 2x2; 32 MFMA/wave/barrier; LDS 48 KB.
// Grid is 512 blocks (2/CU) so 48 KB costs no occupancy. For AO / PO (N=1024).
// ---------------------------------------------------------------------------
template <int EPI, typename OutT>
__global__ __launch_bounds__(256) void gemm_k64(
    const h16* __restrict__ A, const h16* __restrict__ W,
    const float* __restrict__ bias, const float* __restrict__ R,
    OutT* __restrict__ C, int M, int N, int K)
{
    __shared__ h16 As[4][64 * 32];    // 16 KB
    __shared__ h16 Ws[4][128 * 32];   // 32 KB

    const int t = threadIdx.x;
    const int lane = t & 63, wv = t >> 6;
    const int wm = wv >> 1, wn = wv & 1;
    const int c15 = lane & 15, q = lane >> 4;
    const int row0 = blockIdx.y * 64, col0 = blockIdx.x * 128;
    const int arow = t >> 2, acol = (t & 3) << 3;

    f32x4 acc[2][4];
    #pragma unroll
    for (int i = 0; i < 2; ++i)
        #pragma unroll
        for (int j = 0; j < 4; ++j)
            acc[i][j] = (f32x4){0.f, 0.f, 0.f, 0.f};

    for (int k0 = 0; k0 < K; k0 += 128) {
        __syncthreads();
        #pragma unroll
        for (int kk = 0; kk < 4; ++kk) {
            gld_lds16(A + (size_t)(row0 + arow) * K + k0 + kk * 32 + acol,
                      &As[kk][arow * 32 + acol]);
            #pragma unroll
            for (int p = 0; p < 2; ++p) {
                int r = p * 64 + arow;
                gld_lds16(W + (size_t)(col0 + r) * K + k0 + kk * 32 + acol,
                          &Ws[kk][r * 32 + acol]);
            }
        }
        __syncthreads();

        #pragma unroll
        for (int kk = 0; kk < 4; ++kk) {
            half8v af[2], bf[4];
            #pragma unroll
            for (int i = 0; i < 2; ++i)
                af[i] = *(const half8v*)&As[kk][(wm * 32 + i * 16 + c15) * 32 + q * 8];
            #pragma unroll
            for (int j = 0; j < 4; ++j)
                bf[j] = *(const half8v*)&Ws[kk][(wn * 64 + j * 16 + c15) * 32 + q * 8];
            #pragma unroll
            for (int i = 0; i < 2; ++i)
                #pragma unroll
                for (int j = 0; j < 4; ++j)
                    acc[i][j] = __builtin_amdgcn_mfma_f32_16x16x32_f16(af[i], bf[j], acc[i][j], 0, 0, 0);
        }
    }

    #pragma unroll
    for (int i = 0; i < 2; ++i) {
        #pragma unroll
        for (int j = 0; j < 4; ++j) {
            int col = col0 + wn * 64 + j * 16 + c15;
            float bv = bias[col];
            #pragma unroll
            for (int r = 0; r < 4; ++r) {
                int row = row0 + wm * 32 + i * 16 + q * 4 + r;
                size_t off = (size_t)row * N + col;
                float v = acc[i][j][r] + bv;
                if (EPI == 1) v += R[off];
                if (EPI == 2) v = gelu_new(v);
                if (sizeof(OutT) == 2) ((h16*)C)[off] = (h16)v;
                else ((float*)C)[off] = v;
            }
        }
    }
}

// ---------------------------------------------------------------------------
// Causal flash attention v3, fp16 MFMA, O^T formulation.
// Grid (32 bh, 32 q-tiles), ja = 31 - blockIdx.y (long blocks first).
// Block = 4 waves; wave owns 16 query rows (query = c15 lane).
// S^T = K*Q^T -> col=query=c15; O^T = V^T*P^T -> col=query=c15: all softmax
// state (m,l,alpha) is lane-local, zero shuffle broadcasts.
// K double-buffered via global_load_lds; V single-buffer reg-prefetch+scatter.
// LDS 33 KB -> 4 blocks/CU.
// ---------------------------------------------------------------------------
__global__ __launch_bounds__(256, 4) void attn_mfma(const h16* __restrict__ qkv,
                                                    h16* __restrict__ attn) {
    __shared__ h16 Ks[2][2][64 * 32];   // [buf][d-half][key*32+d]   16 KB
    __shared__ h16 Vt[2][64 * 32];      // [key-half][d*32+key]       8 KB
    __shared__ h16 Ps[4][16 * 72];      // [wave][query*72+key]       9 KB

    const int t = threadIdx.x;
    const int lane = t & 63, wv = t >> 6;
    const int c15 = lane & 15, q = lane >> 4;
    const int bh = blockIdx.x, b = bh >> 4, h = bh & 15;
    const int ja = 31 - blockIdx.y;       // long blocks dispatch first
    const int qbase = ja * 64 + wv * 16;  // wave's 16 query rows
    const int SE = 3 * Ec;
    const size_t hbase = (size_t)b * Sc * SE + (size_t)h * (3 * HDc);

    // Q fragment, pre-scaled by 1/sqrt(64) = 0.125 (exact in fp16)
    half8v qf[2];
    #pragma unroll
    for (int kk = 0; kk < 2; ++kk) {
        qf[kk] = *(const half8v*)(qkv + hbase + (size_t)(qbase + c15) * SE + kk * 32 + q * 8);
        qf[kk] *= (h16)0.125f;
    }

    f32x4 O[4];   // O^T: [d-tile], col=query(c15), row=d-local(q*4+r)
    #pragma unroll
    for (int n = 0; n < 4; ++n) O[n] = (f32x4){0.f, 0.f, 0.f, 0.f};
    float mi = -3e38f, li = 0.f;

    const int krow = t >> 2, kcol = (t & 3) << 3;   // K staging (gld_lds16)
    const int vkey = t & 31, vd0 = (t >> 5) << 3;   // V staging
    half8v vreg[2];

    auto stageK = [&](int kt, int bf) {
        #pragma unroll
        for (int p = 0; p < 2; ++p)
            gld_lds16(qkv + hbase + (size_t)(kt * 64 + krow) * SE + HDc + p * 32 + kcol,
                      &Ks[bf][p][krow * 32 + kcol]);
    };
    auto loadV = [&](int kt) {
        #pragma unroll
        for (int p = 0; p < 2; ++p)
            vreg[p] = *(const half8v*)(qkv + hbase +
                        (size_t)(kt * 64 + p * 32 + vkey) * SE + 2 * HDc + vd0);
    };
    auto scatV = [&]() {
        #pragma unroll
        for (int p = 0; p < 2; ++p)
            #pragma unroll
            for (int u = 0; u < 8; ++u)
                Vt[p][(vd0 + u) * 32 + vkey] = vreg[p][u];
    };

    stageK(0, 0);
    loadV(0);
    scatV();
    __syncthreads();

    for (int kt = 0; kt <= ja; ++kt) {
        const int bf = kt & 1;
        if (kt < ja) { stageK(kt + 1, bf ^ 1); loadV(kt + 1); }

        // S^T = K*Q^T : st[j] rows=key-local(q*4+r), col=query(c15)
        f32x4 st[4];
        #pragma unroll
        for (int j = 0; j < 4; ++j) {
            half8v kf0 = *(const half8v*)&Ks[bf][0][(j * 16 + c15) * 32 + q * 8];
            half8v kf1 = *(const half8v*)&Ks[bf][1][(j * 16 + c15) * 32 + q * 8];
            f32x4 z = (f32x4){0.f, 0.f, 0.f, 0.f};
            z = __builtin_amdgcn_mfma_f32_16x16x32_f16(kf0, qf[0], z, 0, 0, 0);
            st[j] = __builtin_amdgcn_mfma_f32_16x16x32_f16(kf1, qf[1], z, 0, 0, 0);
        }

        // causal mask: only the diagonal tile needs it (wave-uniform branch)
        if (kt == ja) {
            const int rowloc = wv * 16 + c15;
            #pragma unroll
            for (int j = 0; j < 4; ++j)
                #pragma unroll
                for (int r = 0; r < 4; ++r)
                    if (j * 16 + q * 4 + r > rowloc) st[j][r] = -3e38f;
        }

        // online softmax; query owned by c15, its 64 keys spread over 4 q-groups
        float mx = mi;
        #pragma unroll
        for (int j = 0; j < 4; ++j)
            #pragma unroll
            for (int r = 0; r < 4; ++r) mx = fmaxf(mx, st[j][r]);
        mx = fmaxf(mx, __shfl_xor(mx, 16, 64));
        mx = fmaxf(mx, __shfl_xor(mx, 32, 64));
        float al = __expf(mi - mx);
        mi = mx;
        float ps = 0.f;
        #pragma unroll
        for (int j = 0; j < 4; ++j) {
            half4v pk;
            #pragma unroll
            for (int r = 0; r < 4; ++r) {
                float p = __expf(st[j][r] - mx);
                ps += p;
                pk[r] = (h16)p;
            }
            *(half4v*)&Ps[wv][c15 * 72 + j * 16 + q * 4] = pk;
        }
        ps += __shfl_xor(ps, 16, 64);
        ps += __shfl_xor(ps, 32, 64);
        li = li * al + ps;

        // O^T += V^T * P^T ; alpha-rescale is lane-local (col=query=c15)
        half8v pb0 = *(const half8v*)&Ps[wv][c15 * 72 + q * 8];
        half8v pb1 = *(const half8v*)&Ps[wv][c15 * 72 + 32 + q * 8];
        #pragma unroll
        for (int n = 0; n < 4; ++n) {
            #pragma unroll
            for (int r = 0; r < 4; ++r) O[n][r] *= al;
            half8v va0 = *(const half8v*)&Vt[0][(n * 16 + c15) * 32 + q * 8];
            half8v va1 = *(const half8v*)&Vt[1][(n * 16 + c15) * 32 + q * 8];
            O[n] = __builtin_amdgcn_mfma_f32_16x16x32_f16(va0, pb0, O[n], 0, 0, 0);
            O[n] = __builtin_amdgcn_mfma_f32_16x16x32_f16(va1, pb1, O[n], 0, 0, 0);
        }

        if (kt < ja) {
            __syncthreads();   // all waves done reading Vt (and Ks[bf])
            scatV();           // write V(kt+1) into single Vt buffer
            __syncthreads();   // Vt + async Ks[bf^1] (vmcnt drain) ready
        }
    }

    // epilogue: query = qbase+c15, d = n*16 + q*4 + r (4 contiguous -> 8B store)
    float rl = 1.0f / li;
    #pragma unroll
    for (int n = 0; n < 4; ++n) {
        half4v o4;
        #pragma unroll
        for (int r = 0; r < 4; ++r) o4[r] = (h16)(O[n][r] * rl);
        *(half4v*)(attn + ((size_t)(b * Sc + qbase + c15)) * Ec + h * HDc + n * 16 + q * 4) = o4;
    }
}

// ---------------------------------------------------------------------------
extern "C" void kernel_launch(void* const* d_in, const int* in_sizes, int n_in,
                              void* d_out, int out_size, void* d_ws, size_t ws_size,
                              hipStream_t stream) {
    const float* x     = (const float*)d_in[0];
    const float* ln1_g = (const float*)d_in[1];
    const float* ln1_b = (const float*)d_in[2];
    const float* ln2_g = (const float*)d_in[3];
    const float* ln2_b = (const float*)d_in[4];
    const float* w_qkv = (const float*)d_in[5];
    const float* b_qkv = (const float*)d_in[6];
    const float* w_ao  = (const float*)d_in[7];
    const float* b_ao  = (const float*)d_in[8];
    const float* w_fc  = (const float*)d_in[9];
    const float* b_fc  = (const float*)d_in[10];
    const float* w_po  = (const float*)d_in[11];
    const float* b_po  = (const float*)d_in[12];
    float* out = (float*)d_out;

    // workspace (80 MB total):
    char* w = (char*)d_ws;
    h16* wqkv = (h16*)(w);             // 6 MB
    h16* wao  = (h16*)(w + 6291456);   // 2 MB
    h16* wfc  = (h16*)(w + 8388608);   // 8 MB
    h16* wpo  = (h16*)(w + 16777216);  // 8 MB
    h16* hb   = (h16*)(w + 25165824);  // 8 MB  (fp16 LN out, reused)
    h16* qkv  = (h16*)(w + 33554432);  // 24 MB
    h16* attn = (h16*)(w + 58720256);  // 8 MB
    float* x1 = (float*)(w + 67108864);// 16 MB
    h16* ff   = qkv;                   // 32 MB alias over qkv+attn (dead)

    dim3 blk(256);

    // weight converts fp32 -> fp16
    cvt_kernel<<<dim3(3 * Ec * Ec / 1024), blk, 0, stream>>>(w_qkv, wqkv, 3 * Ec * Ec);
    cvt_kernel<<<dim3(Ec * Ec / 1024), blk, 0, stream>>>(w_ao, wao, Ec * Ec);
    cvt_kernel<<<dim3(DFFc * Ec / 1024), blk, 0, stream>>>(w_fc, wfc, DFFc * Ec);
    cvt_kernel<<<dim3(Ec * DFFc / 1024), blk, 0, stream>>>(w_po, wpo, Ec * DFFc);

    // 1. hb = LN1(x)
    ln_kernel<<<dim3(ROWS), blk, 0, stream>>>(x, ln1_g, ln1_b, hb);
    // 2. qkv = hb @ w_qkv^T + b_qkv   (fp16 out)
    gemm_mfma<0, h16><<<dim3(3 * Ec / 128, ROWS / 128), blk, 0, stream>>>(
        hb, wqkv, b_qkv, nullptr, qkv, ROWS, 3 * Ec, Ec);
    // 3. attn = causal_flash_attention(qkv)   (fp16 out)
    attn_mfma<<<dim3(Bc * Hc, 32), blk, 0, stream>>>(qkv, attn);
    // 4. x1 = x + attn @ w_ao^T + b_ao  (fp32)
    gemm_k64<1, float><<<dim3(Ec / 128, ROWS / 64), blk, 0, stream>>>(
        attn, wao, b_ao, x, x1, ROWS, Ec, Ec);
    // 5. hb = LN2(x1)
    ln_kernel<<<dim3(ROWS), blk, 0, stream>>>(x1, ln2_g, ln2_b, hb);
    // 6. ff = gelu(hb @ w_fc^T + b_fc)  (fp16)
    gemm_mfma<2, h16><<<dim3(DFFc / 128, ROWS / 128), blk, 0, stream>>>(
        hb, wfc, b_fc, nullptr, ff, ROWS, DFFc, Ec);
    // 7. out = x1 + ff @ w_po^T + b_po  (fp32)
    gemm_k64<1, float><<<dim3(Ec / 128, ROWS / 64), blk, 0, stream>>>(
        ff, wpo, b_po, x1, out, ROWS, Ec, DFFc);
}

// Round 9
// 345.317 us; speedup vs baseline: 10.0809x; 1.0203x over previous
//
#include <hip/hip_runtime.h>
#include <cstddef>
#include <cstdint>

#define Bc 2
#define Sc 2048
#define Ec 1024
#define Hc 16
#define HDc 64
#define DFFc 4096
#define ROWS (Bc * Sc)  // 4096

typedef _Float16 half8v __attribute__((ext_vector_type(8)));  // 8 fp16 (4 VGPR)
typedef _Float16 half4v __attribute__((ext_vector_type(4)));
typedef float f32x4 __attribute__((ext_vector_type(4)));      // MFMA C/D frag
typedef _Float16 h16;

// async global->LDS, 16B per lane. LDS dest must be wave-uniform base + lane*16.
__device__ inline void gld_lds16(const void* g, void* l) {
    __builtin_amdgcn_global_load_lds(
        (const __attribute__((address_space(1))) void*)g,
        (__attribute__((address_space(3))) void*)l, 16, 0, 0);
}

// gelu_new via sigmoid identity: 0.5x(1+tanh(z)) == x*sigmoid(2z).
__device__ inline float gelu_new(float x) {
    float x2 = x * x;
    float u = x * fmaf(0.07135481627362f, x2, 1.5957691216057308f);
    return x / (1.0f + __expf(-u));
}

// ---------------------------------------------------------------------------
// fused fp32 -> fp16 convert for all 4 weights (outputs contiguous in ws)
// ---------------------------------------------------------------------------
__global__ __launch_bounds__(256) void cvt4_kernel(
    const float* __restrict__ a,  // 3M elems  -> blocks [0, 3072)
    const float* __restrict__ b,  // 1M elems  -> blocks [3072, 4096)
    const float* __restrict__ c,  // 4M elems  -> blocks [4096, 8192)
    const float* __restrict__ d,  // 4M elems  -> blocks [8192, 12288)
    h16* __restrict__ out)
{
    int bid = blockIdx.x;
    const float* src;
    size_t obase;
    int base;
    if (bid < 3072)      { src = a; obase = 0;       base = bid; }
    else if (bid < 4096) { src = b; obase = 3145728; base = bid - 3072; }
    else if (bid < 8192) { src = c; obase = 4194304; base = bid - 4096; }
    else                 { src = d; obase = 8388608; base = bid - 8192; }
    int i = base * 1024 + threadIdx.x * 4;
    float4 v = *(const float4*)(src + i);
    half4v o;
    o.x = (h16)v.x; o.y = (h16)v.y; o.z = (h16)v.z; o.w = (h16)v.w;
    *(half4v*)(out + obase + i) = o;
}

// ---------------------------------------------------------------------------
// LayerNorm: fp32 in, fp16 out. One block per row of E=1024.
// ---------------------------------------------------------------------------
__device__ inline float block_sum256(float v, float* sb) {
    #pragma unroll
    for (int o = 32; o > 0; o >>= 1) v += __shfl_down(v, o, 64);
    int lane = threadIdx.x & 63, w = threadIdx.x >> 6;
    if (lane == 0) sb[w] = v;
    __syncthreads();
    float r = sb[0] + sb[1] + sb[2] + sb[3];
    __syncthreads();
    return r;
}

__global__ __launch_bounds__(256) void ln_kernel(const float* __restrict__ x,
                                                 const float* __restrict__ g,
                                                 const float* __restrict__ b,
                                                 h16* __restrict__ out) {
    __shared__ float sb[4];
    int row = blockIdx.x;
    int t = threadIdx.x;
    const float* xr = x + (size_t)row * Ec;
    float4 v = ((const float4*)xr)[t];
    float s = v.x + v.y + v.z + v.w;
    float mu = block_sum256(s, sb) * (1.0f / Ec);
    float dx = v.x - mu, dy = v.y - mu, dz = v.z - mu, dw = v.w - mu;
    float ss = dx * dx + dy * dy + dz * dz + dw * dw;
    float var = block_sum256(ss, sb) * (1.0f / Ec);
    float inv = rsqrtf(var + 1e-5f);
    float4 gv = ((const float4*)g)[t];
    float4 bv = ((const float4*)b)[t];
    half4v o;
    o.x = (h16)(dx * inv * gv.x + bv.x);
    o.y = (h16)(dy * inv * gv.y + bv.y);
    o.z = (h16)(dz * inv * gv.z + bv.z);
    o.w = (h16)(dw * inv * gv.w + bv.w);
    ((half4v*)(out + (size_t)row * Ec))[t] = o;
}

// ---------------------------------------------------------------------------
// fp16 MFMA GEMM (big tile): BM=BN=128, BK=64 as 2 x BK32 sub-buffers.
// 256 threads = 4 waves in 2x2; 32 MFMA/wave/barrier.
// Incremental staging pointers (4 bumps/iter; kk*32 folds into imm offset).
// ---------------------------------------------------------------------------
template <int EPI, typename OutT>
__global__ __launch_bounds__(256) void gemm_mfma(
    const h16* __restrict__ A, const h16* __restrict__ W,
    const float* __restrict__ bias, const float* __restrict__ R,
    OutT* __restrict__ C, int M, int N, int K)
{
    __shared__ h16 As[2][128 * 32];   // 16 KB
    __shared__ h16 Ws[2][128 * 32];   // 16 KB

    const int t = threadIdx.x;
    const int lane = t & 63, wv = t >> 6;
    const int wm = wv >> 1, wn = wv & 1;
    const int c15 = lane & 15, q = lane >> 4;
    const int row0 = blockIdx.y * 128, col0 = blockIdx.x * 128;
    const int arow = t >> 2, acol = (t & 3) << 3;  // staging row / col8

    const h16* ap0 = A + (size_t)(row0 + arow) * K + acol;
    const h16* ap1 = ap0 + (size_t)64 * K;
    const h16* wp0 = W + (size_t)(col0 + arow) * K + acol;
    const h16* wp1 = wp0 + (size_t)64 * K;
    h16* lA0[2]; h16* lA1[2]; h16* lW0[2]; h16* lW1[2];
    #pragma unroll
    for (int kk = 0; kk < 2; ++kk) {
        lA0[kk] = &As[kk][arow * 32 + acol];
        lA1[kk] = &As[kk][(64 + arow) * 32 + acol];
        lW0[kk] = &Ws[kk][arow * 32 + acol];
        lW1[kk] = &Ws[kk][(64 + arow) * 32 + acol];
    }

    f32x4 acc[4][4];
    #pragma unroll
    for (int i = 0; i < 4; ++i)
        #pragma unroll
        for (int j = 0; j < 4; ++j)
            acc[i][j] = (f32x4){0.f, 0.f, 0.f, 0.f};

    for (int k0 = 0; k0 < K; k0 += 64) {
        __syncthreads();
        #pragma unroll
        for (int kk = 0; kk < 2; ++kk) {
            gld_lds16(ap0 + kk * 32, lA0[kk]);
            gld_lds16(ap1 + kk * 32, lA1[kk]);
            gld_lds16(wp0 + kk * 32, lW0[kk]);
            gld_lds16(wp1 + kk * 32, lW1[kk]);
        }
        __syncthreads();

        #pragma unroll
        for (int kk = 0; kk < 2; ++kk) {
            half8v af[4], bf[4];
            #pragma unroll
            for (int i = 0; i < 4; ++i)
                af[i] = *(const half8v*)&As[kk][(wm * 64 + i * 16 + c15) * 32 + q * 8];
            #pragma unroll
            for (int j = 0; j < 4; ++j)
                bf[j] = *(const half8v*)&Ws[kk][(wn * 64 + j * 16 + c15) * 32 + q * 8];
            #pragma unroll
            for (int i = 0; i < 4; ++i)
                #pragma unroll
                for (int j = 0; j < 4; ++j)
                    acc[i][j] = __builtin_amdgcn_mfma_f32_16x16x32_f16(af[i], bf[j], acc[i][j], 0, 0, 0);
        }
        ap0 += 64; ap1 += 64; wp0 += 64; wp1 += 64;
    }

    #pragma unroll
    for (int i = 0; i < 4; ++i) {
        #pragma unroll
        for (int j = 0; j < 4; ++j) {
            int col = col0 + wn * 64 + j * 16 + c15;
            float bv = bias[col];
            #pragma unroll
            for (int r = 0; r < 4; ++r) {
                int row = row0 + wm * 64 + i * 16 + q * 4 + r;
                size_t off = (size_t)row * N + col;
                float v = acc[i][j][r] + bv;
                if (EPI == 1) v += R[off];
                if (EPI == 2) v = gelu_new(v);
                if (sizeof(OutT) == 2) ((h16*)C)[off] = (h16)v;
                else ((float*)C)[off] = v;
            }
        }
    }
}

// ---------------------------------------------------------------------------
// fp16 MFMA GEMM (skinny-N, deep-K): BM=64, BN=128, BK=128 as 4 x BK32
// sub-buffers. XCD-aware swizzle: grid launched 1D (512 = 8 cols x 64 rows);
// the 8 col-blocks of one row-tile share id%8 -> same XCD (round-robin
// dispatch) -> A-tiles served from that XCD's L2. For AO / PO (N=1024).
// ---------------------------------------------------------------------------
template <int EPI, typename OutT>
__global__ __launch_bounds__(256) void gemm_k64(
    const h16* __restrict__ A, const h16* __restrict__ W,
    const float* __restrict__ bias, const float* __restrict__ R,
    OutT* __restrict__ C, int M, int N, int K)
{
    __shared__ h16 As[4][64 * 32];    // 16 KB
    __shared__ h16 Ws[4][128 * 32];   // 32 KB

    const int t = threadIdx.x;
    const int lane = t & 63, wv = t >> 6;
    const int wm = wv >> 1, wn = wv & 1;
    const int c15 = lane & 15, q = lane >> 4;
    // swizzle decode (grid 8x64 flattened): same id%8 => same row group on one XCD
    const int id = blockIdx.x;
    const int cx = id & 7;
    const int kq = id >> 3;
    const int bx = kq & 7;
    const int by = ((kq >> 3) << 3) | cx;
    const int row0 = by * 64, col0 = bx * 128;
    const int arow = t >> 2, acol = (t & 3) << 3;

    const h16* ap  = A + (size_t)(row0 + arow) * K + acol;
    const h16* wp0 = W + (size_t)(col0 + arow) * K + acol;
    const h16* wp1 = wp0 + (size_t)64 * K;
    h16* lA[4]; h16* lW0[4]; h16* lW1[4];
    #pragma unroll
    for (int kk = 0; kk < 4; ++kk) {
        lA[kk]  = &As[kk][arow * 32 + acol];
        lW0[kk] = &Ws[kk][arow * 32 + acol];
        lW1[kk] = &Ws[kk][(64 + arow) * 32 + acol];
    }

    f32x4 acc[2][4];
    #pragma unroll
    for (int i = 0; i < 2; ++i)
        #pragma unroll
        for (int j = 0; j < 4; ++j)
            acc[i][j] = (f32x4){0.f, 0.f, 0.f, 0.f};

    for (int k0 = 0; k0 < K; k0 += 128) {
        __syncthreads();
        #pragma unroll
        for (int kk = 0; kk < 4; ++kk) {
            gld_lds16(ap  + kk * 32, lA[kk]);
            gld_lds16(wp0 + kk * 32, lW0[kk]);
            gld_lds16(wp1 + kk * 32, lW1[kk]);
        }
        __syncthreads();

        #pragma unroll
        for (int kk = 0; kk < 4; ++kk) {
            half8v af[2], bf[4];
            #pragma unroll
            for (int i = 0; i < 2; ++i)
                af[i] = *(const half8v*)&As[kk][(wm * 32 + i * 16 + c15) * 32 + q * 8];
            #pragma unroll
            for (int j = 0; j < 4; ++j)
                bf[j] = *(const half8v*)&Ws[kk][(wn * 64 + j * 16 + c15) * 32 + q * 8];
            #pragma unroll
            for (int i = 0; i < 2; ++i)
                #pragma unroll
                for (int j = 0; j < 4; ++j)
                    acc[i][j] = __builtin_amdgcn_mfma_f32_16x16x32_f16(af[i], bf[j], acc[i][j], 0, 0, 0);
        }
        ap += 128; wp0 += 128; wp1 += 128;
    }

    #pragma unroll
    for (int i = 0; i < 2; ++i) {
        #pragma unroll
        for (int j = 0; j < 4; ++j) {
            int col = col0 + wn * 64 + j * 16 + c15;
            float bv = bias[col];
            #pragma unroll
            for (int r = 0; r < 4; ++r) {
                int row = row0 + wm * 32 + i * 16 + q * 4 + r;
                size_t off = (size_t)row * N + col;
                float v = acc[i][j][r] + bv;
                if (EPI == 1) v += R[off];
                if (EPI == 2) v = gelu_new(v);
                if (sizeof(OutT) == 2) ((h16*)C)[off] = (h16)v;
                else ((float*)C)[off] = v;
            }
        }
    }
}

// ---------------------------------------------------------------------------
// Causal flash attention v3, fp16 MFMA, O^T formulation.
// Grid (32 bh, 32 q-tiles), ja = 31 - blockIdx.y (long blocks first).
// S^T = K*Q^T and O^T = V^T*P^T -> col=query=c15: softmax state lane-local.
// K double-buffered via global_load_lds; V single-buffer reg-prefetch+scatter.
// ---------------------------------------------------------------------------
__global__ __launch_bounds__(256, 4) void attn_mfma(const h16* __restrict__ qkv,
                                                    h16* __restrict__ attn) {
    __shared__ h16 Ks[2][2][64 * 32];   // [buf][d-half][key*32+d]   16 KB
    __shared__ h16 Vt[2][64 * 32];      // [key-half][d*32+key]       8 KB
    __shared__ h16 Ps[4][16 * 72];      // [wave][query*72+key]       9 KB

    const int t = threadIdx.x;
    const int lane = t & 63, wv = t >> 6;
    const int c15 = lane & 15, q = lane >> 4;
    const int bh = blockIdx.x, b = bh >> 4, h = bh & 15;
    const int ja = 31 - blockIdx.y;       // long blocks dispatch first
    const int qbase = ja * 64 + wv * 16;  // wave's 16 query rows
    const int SE = 3 * Ec;
    const size_t hbase = (size_t)b * Sc * SE + (size_t)h * (3 * HDc);

    // Q fragment, pre-scaled by 1/sqrt(64) = 0.125 (exact in fp16)
    half8v qf[2];
    #pragma unroll
    for (int kk = 0; kk < 2; ++kk) {
        qf[kk] = *(const half8v*)(qkv + hbase + (size_t)(qbase + c15) * SE + kk * 32 + q * 8);
        qf[kk] *= (h16)0.125f;
    }

    f32x4 O[4];   // O^T: [d-tile], col=query(c15), row=d-local(q*4+r)
    #pragma unroll
    for (int n = 0; n < 4; ++n) O[n] = (f32x4){0.f, 0.f, 0.f, 0.f};
    float mi = -3e38f, li = 0.f;

    const int krow = t >> 2, kcol = (t & 3) << 3;   // K staging (gld_lds16)
    const int vkey = t & 31, vd0 = (t >> 5) << 3;   // V staging
    half8v vreg[2];

    auto stageK = [&](int kt, int bf) {
        #pragma unroll
        for (int p = 0; p < 2; ++p)
            gld_lds16(qkv + hbase + (size_t)(kt * 64 + krow) * SE + HDc + p * 32 + kcol,
                      &Ks[bf][p][krow * 32 + kcol]);
    };
    auto loadV = [&](int kt) {
        #pragma unroll
        for (int p = 0; p < 2; ++p)
            vreg[p] = *(const half8v*)(qkv + hbase +
                        (size_t)(kt * 64 + p * 32 + vkey) * SE + 2 * HDc + vd0);
    };
    auto scatV = [&]() {
        #pragma unroll
        for (int p = 0; p < 2; ++p)
            #pragma unroll
            for (int u = 0; u < 8; ++u)
                Vt[p][(vd0 + u) * 32 + vkey] = vreg[p][u];
    };

    stageK(0, 0);
    loadV(0);
    scatV();
    __syncthreads();

    for (int kt = 0; kt <= ja; ++kt) {
        const int bf = kt & 1;
        if (kt < ja) { stageK(kt + 1, bf ^ 1); loadV(kt + 1); }

        // S^T = K*Q^T : st[j] rows=key-local(q*4+r), col=query(c15)
        f32x4 st[4];
        #pragma unroll
        for (int j = 0; j < 4; ++j) {
            half8v kf0 = *(const half8v*)&Ks[bf][0][(j * 16 + c15) * 32 + q * 8];
            half8v kf1 = *(const half8v*)&Ks[bf][1][(j * 16 + c15) * 32 + q * 8];
            f32x4 z = (f32x4){0.f, 0.f, 0.f, 0.f};
            z = __builtin_amdgcn_mfma_f32_16x16x32_f16(kf0, qf[0], z, 0, 0, 0);
            st[j] = __builtin_amdgcn_mfma_f32_16x16x32_f16(kf1, qf[1], z, 0, 0, 0);
        }

        // causal mask: only the diagonal tile needs it (wave-uniform branch)
        if (kt == ja) {
            const int rowloc = wv * 16 + c15;
            #pragma unroll
            for (int j = 0; j < 4; ++j)
                #pragma unroll
                for (int r = 0; r < 4; ++r)
                    if (j * 16 + q * 4 + r > rowloc) st[j][r] = -3e38f;
        }

        // online softmax; query owned by c15, its 64 keys spread over 4 q-groups
        float mx = mi;
        #pragma unroll
        for (int j = 0; j < 4; ++j)
            #pragma unroll
            for (int r = 0; r < 4; ++r) mx = fmaxf(mx, st[j][r]);
        mx = fmaxf(mx, __shfl_xor(mx, 16, 64));
        mx = fmaxf(mx, __shfl_xor(mx, 32, 64));
        float al = __expf(mi - mx);
        mi = mx;
        float ps = 0.f;
        #pragma unroll
        for (int j = 0; j < 4; ++j) {
            half4v pk;
            #pragma unroll
            for (int r = 0; r < 4; ++r) {
                float p = __expf(st[j][r] - mx);
                ps += p;
                pk[r] = (h16)p;
            }
            *(half4v*)&Ps[wv][c15 * 72 + j * 16 + q * 4] = pk;
        }
        ps += __shfl_xor(ps, 16, 64);
        ps += __shfl_xor(ps, 32, 64);
        li = li * al + ps;

        // O^T += V^T * P^T ; alpha-rescale is lane-local (col=query=c15)
        half8v pb0 = *(const half8v*)&Ps[wv][c15 * 72 + q * 8];
        half8v pb1 = *(const half8v*)&Ps[wv][c15 * 72 + 32 + q * 8];
        #pragma unroll
        for (int n = 0; n < 4; ++n) {
            #pragma unroll
            for (int r = 0; r < 4; ++r) O[n][r] *= al;
            half8v va0 = *(const half8v*)&Vt[0][(n * 16 + c15) * 32 + q * 8];
            half8v va1 = *(const half8v*)&Vt[1][(n * 16 + c15) * 32 + q * 8];
            O[n] = __builtin_amdgcn_mfma_f32_16x16x32_f16(va0, pb0, O[n], 0, 0, 0);
            O[n] = __builtin_amdgcn_mfma_f32_16x16x32_f16(va1, pb1, O[n], 0, 0, 0);
        }

        if (kt < ja) {
            __syncthreads();   // all waves done reading Vt (and Ks[bf])
            scatV();           // write V(kt+1) into single Vt buffer
            __syncthreads();   // Vt + async Ks[bf^1] (vmcnt drain) ready
        }
    }

    // epilogue: query = qbase+c15, d = n*16 + q*4 + r (4 contiguous -> 8B store)
    float rl = 1.0f / li;
    #pragma unroll
    for (int n = 0; n < 4; ++n) {
        half4v o4;
        #pragma unroll
        for (int r = 0; r < 4; ++r) o4[r] = (h16)(O[n][r] * rl);
        *(half4v*)(attn + ((size_t)(b * Sc + qbase + c15)) * Ec + h * HDc + n * 16 + q * 4) = o4;
    }
}

// ---------------------------------------------------------------------------
extern "C" void kernel_launch(void* const* d_in, const int* in_sizes, int n_in,
                              void* d_out, int out_size, void* d_ws, size_t ws_size,
                              hipStream_t stream) {
    const float* x     = (const float*)d_in[0];
    const float* ln1_g = (const float*)d_in[1];
    const float* ln1_b = (const float*)d_in[2];
    const float* ln2_g = (const float*)d_in[3];
    const float* ln2_b = (const float*)d_in[4];
    const float* w_qkv = (const float*)d_in[5];
    const float* b_qkv = (const float*)d_in[6];
    const float* w_ao  = (const float*)d_in[7];
    const float* b_ao  = (const float*)d_in[8];
    const float* w_fc  = (const float*)d_in[9];
    const float* b_fc  = (const float*)d_in[10];
    const float* w_po  = (const float*)d_in[11];
    const float* b_po  = (const float*)d_in[12];
    float* out = (float*)d_out;

    // workspace (80 MB total):
    char* w = (char*)d_ws;
    h16* wqkv = (h16*)(w);             // 6 MB   (cvt4 outputs contiguous)
    h16* wao  = (h16*)(w + 6291456);   // 2 MB
    h16* wfc  = (h16*)(w + 8388608);   // 8 MB
    h16* wpo  = (h16*)(w + 16777216);  // 8 MB
    h16* hb   = (h16*)(w + 25165824);  // 8 MB  (fp16 LN out, reused)
    h16* qkv  = (h16*)(w + 33554432);  // 24 MB
    h16* attn = (h16*)(w + 58720256);  // 8 MB
    float* x1 = (float*)(w + 67108864);// 16 MB
    h16* ff   = qkv;                   // 32 MB alias over qkv+attn (dead)

    dim3 blk(256);

    // fused weight converts fp32 -> fp16 (one launch)
    cvt4_kernel<<<dim3(12288), blk, 0, stream>>>(w_qkv, w_ao, w_fc, w_po, wqkv);

    // 1. hb = LN1(x)
    ln_kernel<<<dim3(ROWS), blk, 0, stream>>>(x, ln1_g, ln1_b, hb);
    // 2. qkv = hb @ w_qkv^T + b_qkv   (fp16 out)
    gemm_mfma<0, h16><<<dim3(3 * Ec / 128, ROWS / 128), blk, 0, stream>>>(
        hb, wqkv, b_qkv, nullptr, qkv, ROWS, 3 * Ec, Ec);
    // 3. attn = causal_flash_attention(qkv)   (fp16 out)
    attn_mfma<<<dim3(Bc * Hc, 32), blk, 0, stream>>>(qkv, attn);
    // 4. x1 = x + attn @ w_ao^T + b_ao  (fp32)   [1D grid, XCD swizzle]
    gemm_k64<1, float><<<dim3(512), blk, 0, stream>>>(
        attn, wao, b_ao, x, x1, ROWS, Ec, Ec);
    // 5. hb = LN2(x1)
    ln_kernel<<<dim3(ROWS), blk, 0, stream>>>(x1, ln2_g, ln2_b, hb);
    // 6. ff = gelu(hb @ w_fc^T + b_fc)  (fp16)
    gemm_mfma<2, h16><<<dim3(DFFc / 128, ROWS / 128), blk, 0, stream>>>(
        hb, wfc, b_fc, nullptr, ff, ROWS, DFFc, Ec);
    // 7. out = x1 + ff @ w_po^T + b_po  (fp32)   [1D grid, XCD swizzle]
    gemm_k64<1, float><<<dim3(512), blk, 0, stream>>>(
        ff, wpo, b_po, x1, out, ROWS, Ec, DFFc);
}